// Round 1
// baseline (842.870 us; speedup 1.0000x reference)
//
#include <hip/hip_runtime.h>

typedef short bf8 __attribute__((ext_vector_type(8)));
typedef float f32x4 __attribute__((ext_vector_type(4)));

static __device__ __forceinline__ unsigned short f2bf(float f) {
  unsigned u = __float_as_uint(f);
  unsigned r = u + 0x7FFFu + ((u >> 16) & 1u);
  return (unsigned short)(r >> 16);
}
static __device__ __forceinline__ float bf2f(unsigned short h) {
  return __uint_as_float(((unsigned)h) << 16);
}
// order-preserving float -> u32 key (for atomicMax)
static __device__ __forceinline__ unsigned fkey(float f) {
  unsigned u = __float_as_uint(f);
  return (u & 0x80000000u) ? ~u : (u | 0x80000000u);
}
static __device__ __forceinline__ float kdec(unsigned k) {
  unsigned u = (k & 0x80000000u) ? (k & 0x7FFFFFFFu) : ~k;
  return __uint_as_float(u);
}

// unfold(k=3,pad=1,stride=1) value: row d = (cc*3+ki)*3+kj, col m = i*S+j, src [C][S][S]
static __device__ __forceinline__ float uf3(const float* __restrict__ src, int lgS, int d, int m) {
  const int S = 1 << lgS;
  int cc = d / 9;
  int r9 = d - cc * 9;
  int ki = r9 / 3;
  int kj = r9 - ki * 3;
  int i = (m >> lgS) + ki - 1;
  int j = (m & (S - 1)) + kj - 1;
  if ((unsigned)i >= (unsigned)S || (unsigned)j >= (unsigned)S) return 0.f;
  return src[((size_t)cc << (2 * lgS)) + ((size_t)i << lgS) + j];
}

// ---------------- prep kernels ----------------

// per-column 1/max(||col||,eps) of unfold(src,3,1,1), S=32, CKK=2304
__global__ __launch_bounds__(256) void k_colnorm(const float* __restrict__ src, float* __restrict__ scale) {
  int m = blockIdx.x;
  float s = 0.f;
  for (int d = threadIdx.x; d < 2304; d += 256) {
    float v = uf3(src, 5, d, m);
    s += v * v;
  }
  __shared__ float red[256];
  red[threadIdx.x] = s; __syncthreads();
  for (int o = 128; o > 0; o >>= 1) { if (threadIdx.x < o) red[threadIdx.x] += red[threadIdx.x + o]; __syncthreads(); }
  if (threadIdx.x == 0) scale[m] = 1.f / fmaxf(sqrtf(red[0]), 1e-12f);
}

// normalized unfold, f32, layout [d][m] (d=2304, m=1024)
__global__ __launch_bounds__(256) void k_pass2_dm(const float* __restrict__ src, const float* __restrict__ scale, float* __restrict__ out) {
  int id = blockIdx.x * 256 + threadIdx.x;
  int d = id >> 10, m = id & 1023;
  out[id] = uf3(src, 5, d, m) * scale[m];
}
// normalized unfold, bf16, layout [m][d]
__global__ __launch_bounds__(256) void k_pass2_md_bf(const float* __restrict__ src, const float* __restrict__ scale, unsigned short* __restrict__ out) {
  int id = blockIdx.x * 256 + threadIdx.x;
  int m = id / 2304, d = id - m * 2304;
  out[id] = f2bf(uf3(src, 5, d, m) * scale[m]);
}
// plain unfold -> bf16, layout [n][c]
__global__ __launch_bounds__(256) void k_unfold_bf(const float* __restrict__ src, unsigned short* __restrict__ out, int lgS, int CK, int total) {
  int id = blockIdx.x * 256 + threadIdx.x;
  if (id >= total) return;
  int n = id / CK, c = id - n * CK;
  out[id] = f2bf(uf3(src, lgS, c, n));
}
// W [2304][Cw] f32 -> Wt [Cw][2304] bf16
__global__ __launch_bounds__(256) void k_wtrans(const float* __restrict__ W, unsigned short* __restrict__ Wt, int Cw, int total) {
  int id = blockIdx.x * 256 + threadIdx.x;
  if (id >= total) return;
  int d = id / Cw, c = id - d * Cw;
  Wt[(size_t)c * 2304 + d] = f2bf(W[id]);
}
// bw[c] = sum_d b[d]*W[d][c]
__global__ __launch_bounds__(256) void k_bw(const float* __restrict__ W, const float* __restrict__ b, float* __restrict__ bw, int Cw) {
  int c = blockIdx.x * 256 + threadIdx.x;
  if (c >= Cw) return;
  float s = 0.f;
  for (int d = 0; d < 2304; ++d) s += b[d] * W[(size_t)d * Cw + c];
  bw[c] = s;
}
// bb[0]=||b1||^2, bb[1]=||b2||^2
__global__ __launch_bounds__(256) void k_bb(const float* __restrict__ b1, const float* __restrict__ b2, float* __restrict__ bb) {
  const float* b = blockIdx.x ? b2 : b1;
  float s = 0.f;
  for (int d = threadIdx.x; d < 2304; d += 256) s += b[d] * b[d];
  __shared__ float red[256];
  red[threadIdx.x] = s; __syncthreads();
  for (int o = 128; o > 0; o >>= 1) { if (threadIdx.x < o) red[threadIdx.x] += red[threadIdx.x + o]; __syncthreads(); }
  if (threadIdx.x == 0) bb[blockIdx.x] = red[0];
}
// bl2[m] = b1 . lr3n[:,m] ; bl1[m] = b2 . lr3n[:,m]
__global__ __launch_bounds__(256) void k_bl(const float* __restrict__ lr3n, const float* __restrict__ b1, const float* __restrict__ b2,
                                            float* __restrict__ bl2, float* __restrict__ bl1) {
  int m = blockIdx.x * 256 + threadIdx.x;
  float s2 = 0.f, s1 = 0.f;
  for (int d = 0; d < 2304; ++d) {
    float v = lr3n[(size_t)d * 1024 + m];
    s2 += b1[d] * v; s1 += b2[d] * v;
  }
  bl2[m] = s2; bl1[m] = s1;
}

// ---------------- bf16 MFMA GEMM, TN form: C[i][j] = sum_k A[i][k]*Bt[j][k] ----------------
// BM=BN=BK=64, 256 threads (4 waves). All of M,N,K divisible by 64.
// EPI 0: store bf16 C[M][N]
// EPI 1: normsq[i] += sum_j C[i][j]*A[i][j]   (requires N==K; Bt symmetric Gram)
// EPI 2: skey[j] = max_i fkey((C[i][j]+bl[j])*ninv[i])
template <int EPI>
__global__ __launch_bounds__(256) void k_gemm(const unsigned short* __restrict__ A,
                                              const unsigned short* __restrict__ Bt,
                                              unsigned short* __restrict__ C,
                                              int M, int N, int K,
                                              const float* __restrict__ bl,
                                              const float* __restrict__ ninv,
                                              float* __restrict__ normsq,
                                              unsigned* __restrict__ skey) {
  __shared__ __align__(16) unsigned short As[64 * 64];
  __shared__ __align__(16) unsigned short Bs[64 * 64];
  __shared__ unsigned colkey[64];
  const int tid = threadIdx.x;
  const int l = tid & 63;
  const int w = tid >> 6;
  const int m0 = blockIdx.y * 64;
  const int n0 = blockIdx.x * 64;
  if (EPI == 2 && tid < 64) colkey[tid] = 0u;

  f32x4 acc[4] = {{0.f,0.f,0.f,0.f},{0.f,0.f,0.f,0.f},{0.f,0.f,0.f,0.f},{0.f,0.f,0.f,0.f}};

  // staging: thread -> (row sr, k8-pair sj0); LDS layout swizzled: (r, k8) at r*64 + ((k8 ^ (r&7))*8)
  const int sr = tid >> 2;
  const int sj0 = (tid & 3) * 2;
  const int swz = sr & 7;
  const int lof0 = sr * 64 + ((sj0 ^ swz) * 8);
  const int lof1 = sr * 64 + (((sj0 + 1) ^ swz) * 8);
  const size_t arow = (size_t)(m0 + sr) * (size_t)K;
  const size_t brow = (size_t)(n0 + sr) * (size_t)K;

  const int mr = l & 15;
  const int kg = l >> 4;
  const int rsw = mr & 7;
  const int abase = (w * 16 + mr) * 64;

  for (int kb = 0; kb < K; kb += 64) {
    bf8 a0 = *(const bf8*)(A + arow + kb + sj0 * 8);
    bf8 a1 = *(const bf8*)(A + arow + kb + sj0 * 8 + 8);
    bf8 b0 = *(const bf8*)(Bt + brow + kb + sj0 * 8);
    bf8 b1 = *(const bf8*)(Bt + brow + kb + sj0 * 8 + 8);
    __syncthreads();
    *(bf8*)(&As[lof0]) = a0;
    *(bf8*)(&As[lof1]) = a1;
    *(bf8*)(&Bs[lof0]) = b0;
    *(bf8*)(&Bs[lof1]) = b1;
    __syncthreads();
#pragma unroll
    for (int s = 0; s < 2; ++s) {
      const int ksw = ((s * 4 + kg) ^ rsw) * 8;
      bf8 af = *(const bf8*)(&As[abase + ksw]);
#pragma unroll
      for (int fi = 0; fi < 4; ++fi) {
        bf8 bv = *(const bf8*)(&Bs[(fi * 16 + mr) * 64 + ksw]);
        acc[fi] = __builtin_amdgcn_mfma_f32_16x16x32_bf16(af, bv, acc[fi], 0, 0, 0);
      }
    }
  }

  // C/D layout: col = lane&15 (within 16x16 frag), row = (lane>>4)*4 + reg
  const int gr0 = m0 + w * 16 + kg * 4;
  const int gc0 = n0 + mr;
  if (EPI == 0) {
#pragma unroll
    for (int fi = 0; fi < 4; ++fi)
#pragma unroll
      for (int e = 0; e < 4; ++e)
        C[(size_t)(gr0 + e) * (size_t)N + (gc0 + fi * 16)] = f2bf(acc[fi][e]);
  } else if (EPI == 1) {
    float rp[4] = {0.f, 0.f, 0.f, 0.f};
#pragma unroll
    for (int fi = 0; fi < 4; ++fi)
#pragma unroll
      for (int e = 0; e < 4; ++e)
        rp[e] += acc[fi][e] * bf2f(A[(size_t)(gr0 + e) * (size_t)K + (gc0 + fi * 16)]);
#pragma unroll
    for (int off = 1; off < 16; off <<= 1) {
#pragma unroll
      for (int e = 0; e < 4; ++e) rp[e] += __shfl_xor(rp[e], off);
    }
    if (mr == 0) {
#pragma unroll
      for (int e = 0; e < 4; ++e) atomicAdd(&normsq[gr0 + e], rp[e]);
    }
  } else {
    float nv[4];
#pragma unroll
    for (int e = 0; e < 4; ++e) nv[e] = ninv[gr0 + e];
#pragma unroll
    for (int fi = 0; fi < 4; ++fi) {
      float blv = bl[gc0 + fi * 16];
      float mx = -3.0e38f;
#pragma unroll
      for (int e = 0; e < 4; ++e) mx = fmaxf(mx, (acc[fi][e] + blv) * nv[e]);
      atomicMax(&colkey[mr + fi * 16], fkey(mx));
    }
    __syncthreads();
    if (tid < 64) atomicMax(&skey[n0 + tid], colkey[tid]);
  }
}

// finalize norms: ninv[n] = 1/max(sqrt(max(normsq[n] + 2*bw.u_n + bb,0)),eps)
__global__ __launch_bounds__(128) void k_normfin(const unsigned short* __restrict__ U, const float* __restrict__ bw,
                                                 const float* __restrict__ bb, int which,
                                                 const float* __restrict__ normsq, float* __restrict__ ninv, int K) {
  int n = blockIdx.x;
  float s = 0.f;
  for (int c = threadIdx.x; c < K; c += 128) s += bw[c] * bf2f(U[(size_t)n * K + c]);
  __shared__ float red[128];
  red[threadIdx.x] = s; __syncthreads();
  for (int o = 64; o > 0; o >>= 1) { if (threadIdx.x < o) red[threadIdx.x] += red[threadIdx.x + o]; __syncthreads(); }
  if (threadIdx.x == 0) {
    float t = normsq[n] + 2.f * red[0] + bb[which];
    float nr = sqrtf(fmaxf(t, 0.f));
    ninv[n] = 1.f / fmaxf(nr, 1e-12f);
  }
}

// ---------------- fp32 R3^T GEMM: R3t[m][n] = sum_d lr3n[d][m]*u3n[d][n] ----------------
__global__ __launch_bounds__(256) void k_gemm_r3(const float* __restrict__ Apm, const float* __restrict__ Bpn,
                                                 float* __restrict__ R3t) {
  __shared__ float As[16][68];
  __shared__ float Bs[16][68];
  const int tid = threadIdx.x;
  const int tx = tid & 15, ty = tid >> 4;
  const int m0 = blockIdx.y * 64, n0 = blockIdx.x * 64;
  float acc[4][4] = {};
  for (int kb = 0; kb < 2304; kb += 16) {
    __syncthreads();
#pragma unroll
    for (int i = 0; i < 4; ++i) {
      int idx = tid + i * 256;
      int kk = idx >> 6, mm = idx & 63;
      As[kk][mm] = Apm[(size_t)(kb + kk) * 1024 + m0 + mm];
      Bs[kk][mm] = Bpn[(size_t)(kb + kk) * 1024 + n0 + mm];
    }
    __syncthreads();
#pragma unroll
    for (int kk = 0; kk < 16; ++kk) {
      float a[4], b[4];
#pragma unroll
      for (int e = 0; e < 4; ++e) { a[e] = As[kk][ty * 4 + e]; b[e] = Bs[kk][tx * 4 + e]; }
#pragma unroll
      for (int i = 0; i < 4; ++i)
#pragma unroll
        for (int j = 0; j < 4; ++j) acc[i][j] = fmaf(a[i], b[j], acc[i][j]);
    }
  }
#pragma unroll
  for (int i = 0; i < 4; ++i)
#pragma unroll
    for (int j = 0; j < 4; ++j)
      R3t[(size_t)(m0 + ty * 4 + i) * 1024 + (n0 + tx * 4 + j)] = acc[i][j];
}

// per-row max + first-argmax over n
__global__ __launch_bounds__(256) void k_argmax3(const float* __restrict__ R3t, float* __restrict__ s3, int* __restrict__ arg) {
  int m = blockIdx.x;
  const float* row = R3t + (size_t)m * 1024;
  float best = -3.0e38f; int bi = 0;
  for (int n = threadIdx.x; n < 1024; n += 256) {
    float v = row[n];
    if (v > best) { best = v; bi = n; }
  }
  __shared__ float bv[256]; __shared__ int bidx[256];
  bv[threadIdx.x] = best; bidx[threadIdx.x] = bi;
  __syncthreads();
  for (int o = 128; o > 0; o >>= 1) {
    if (threadIdx.x < o) {
      float ov = bv[threadIdx.x + o]; int oi = bidx[threadIdx.x + o];
      if (ov > bv[threadIdx.x] || (ov == bv[threadIdx.x] && oi < bidx[threadIdx.x])) {
        bv[threadIdx.x] = ov; bidx[threadIdx.x] = oi;
      }
    }
    __syncthreads();
  }
  if (threadIdx.x == 0) { s3[m] = bv[0]; arg[m] = bidx[0]; }
}

__global__ __launch_bounds__(256) void k_finS(const unsigned* __restrict__ k1, const unsigned* __restrict__ k2, float* __restrict__ out) {
  int t = blockIdx.x * 256 + threadIdx.x;
  if (t < 1024) { out[t] = kdec(k1[t]); out[1024 + t] = kdec(k2[t]); }
}

// ---------------- gather + fold ----------------
__global__ __launch_bounds__(256) void k_tfold3(const float* __restrict__ ref, const int* __restrict__ arg, float* __restrict__ out) {
  int id = blockIdx.x * 256 + threadIdx.x;
  int c = id >> 10, rem = id & 1023;
  int y = rem >> 5, x = rem & 31;
  float s = 0.f;
#pragma unroll
  for (int ki = 0; ki < 3; ++ki) {
    int i = y + 1 - ki;
    if ((unsigned)i >= 32u) continue;
#pragma unroll
    for (int kj = 0; kj < 3; ++kj) {
      int j = x + 1 - kj;
      if ((unsigned)j >= 32u) continue;
      int n2 = arg[i * 32 + j];
      int rr = (n2 >> 5) + ki - 1, cc = (n2 & 31) + kj - 1;
      if ((unsigned)rr < 32u && (unsigned)cc < 32u) s += ref[(size_t)c * 1024 + rr * 32 + cc];
    }
  }
  out[id] = s * (1.f / 9.f);
}
__global__ __launch_bounds__(256) void k_tfold2(const float* __restrict__ ref, const int* __restrict__ arg, float* __restrict__ out) {
  int id = blockIdx.x * 256 + threadIdx.x;
  int c = id >> 12, rem = id & 4095;
  int y = rem >> 6, x = rem & 63;
  float s = 0.f;
#pragma unroll
  for (int ki = 0; ki < 6; ++ki) {
    int t = y + 2 - ki;
    if (t < 0 || (t & 1)) continue;
    int i = t >> 1;
    if (i >= 32) continue;
#pragma unroll
    for (int kj = 0; kj < 6; ++kj) {
      int t2 = x + 2 - kj;
      if (t2 < 0 || (t2 & 1)) continue;
      int j = t2 >> 1;
      if (j >= 32) continue;
      int n2 = arg[i * 32 + j];
      int rr = (n2 >> 5) * 2 + ki - 2, cc = (n2 & 31) * 2 + kj - 2;
      if ((unsigned)rr < 64u && (unsigned)cc < 64u) s += ref[(size_t)c * 4096 + rr * 64 + cc];
    }
  }
  out[id] = s * (1.f / 9.f);
}
__global__ __launch_bounds__(256) void k_tfold1(const float* __restrict__ ref, const int* __restrict__ arg, float* __restrict__ out) {
  int id = blockIdx.x * 256 + threadIdx.x;
  int c = id >> 14, rem = id & 16383;
  int y = rem >> 7, x = rem & 127;
  float s = 0.f;
#pragma unroll
  for (int ki = 0; ki < 12; ++ki) {
    int t = y + 4 - ki;
    if (t < 0 || (t & 3)) continue;
    int i = t >> 2;
    if (i >= 32) continue;
#pragma unroll
    for (int kj = 0; kj < 12; ++kj) {
      int t2 = x + 4 - kj;
      if (t2 < 0 || (t2 & 3)) continue;
      int j = t2 >> 2;
      if (j >= 32) continue;
      int n2 = arg[i * 32 + j];
      int rr = (n2 >> 5) * 4 + ki - 4, cc = (n2 & 31) * 4 + kj - 4;
      if ((unsigned)rr < 128u && (unsigned)cc < 128u) s += ref[(size_t)c * 16384 + rr * 128 + cc];
    }
  }
  out[id] = s * (1.f / 9.f);
}

// ---------------- workspace layout (bytes) ----------------
static constexpr size_t OFF_NORMSQ2 = 0;              // 4096 f32
static constexpr size_t OFF_NORMSQ1 = 16384;          // 16384 f32
static constexpr size_t OFF_S1KEY   = 81920;          // 1024 u32
static constexpr size_t OFF_S2KEY   = 86016;          // 1024 u32
static constexpr size_t ZERO_BYTES  = 90112;
static constexpr size_t OFF_LR3N    = 90112;                    // f32 [2304][1024]
static constexpr size_t OFF_U3N     = OFF_LR3N   + 9437184;     // f32 [2304][1024]
static constexpr size_t OFF_LR3NBT  = OFF_U3N    + 9437184;     // bf16 [1024][2304]
static constexpr size_t OFF_U2B     = OFF_LR3NBT + 4718592;     // bf16 [4096][1152]
static constexpr size_t OFF_U1B     = OFF_U2B    + 9437184;     // bf16 [16384][576]
static constexpr size_t OFF_W1T     = OFF_U1B    + 18874368;    // bf16 [1152][2304]
static constexpr size_t OFF_W2T     = OFF_W1T    + 5308416;     // bf16 [576][2304]
static constexpr size_t OFF_A2      = OFF_W2T    + 2654208;     // bf16 [1152][1152]
static constexpr size_t OFF_A1      = OFF_A2     + 2654208;     // bf16 [576][576]
static constexpr size_t OFF_M2T     = OFF_A1     + 663552;      // bf16 [1024][1152]
static constexpr size_t OFF_M1T     = OFF_M2T    + 2359296;     // bf16 [1024][576]
static constexpr size_t OFF_R3T     = OFF_M1T    + 1179648;     // f32 [1024][1024]
static constexpr size_t OFF_R3ARG   = OFF_R3T    + 4194304;     // int [1024]
static constexpr size_t OFF_SCLR    = OFF_R3ARG  + 4096;        // f32 [1024]
static constexpr size_t OFF_SCU3    = OFF_SCLR   + 4096;        // f32 [1024]
static constexpr size_t OFF_BW2     = OFF_SCU3   + 4096;        // f32 [1152]
static constexpr size_t OFF_BW1     = OFF_BW2    + 4608;        // f32 [576]
static constexpr size_t OFF_BL2     = OFF_BW1    + 2304;        // f32 [1024]
static constexpr size_t OFF_BL1     = OFF_BL2    + 4096;        // f32 [1024]
static constexpr size_t OFF_BB      = OFF_BL1    + 4096;        // f32 [2]
static constexpr size_t OFF_N2INV   = OFF_BB     + 256;         // f32 [4096]
static constexpr size_t OFF_N1INV   = OFF_N2INV  + 16384;       // f32 [16384]

extern "C" void kernel_launch(void* const* d_in, const int* in_sizes, int n_in,
                              void* d_out, int out_size, void* d_ws, size_t ws_size,
                              hipStream_t stream) {
  (void)in_sizes; (void)n_in; (void)out_size; (void)ws_size;
  const float* lrsr3  = (const float*)d_in[0];
  const float* rsr1   = (const float*)d_in[1];
  const float* rsr2   = (const float*)d_in[2];
  const float* rsr3   = (const float*)d_in[3];
  const float* ref1   = (const float*)d_in[4];
  const float* ref2   = (const float*)d_in[5];
  const float* ref3   = (const float*)d_in[6];
  const float* W1     = (const float*)d_in[7];
  const float* b1     = (const float*)d_in[8];
  const float* W2     = (const float*)d_in[9];
  const float* b2     = (const float*)d_in[10];
  float* out = (float*)d_out;
  char* ws = (char*)d_ws;

  float*          normsq2 = (float*)(ws + OFF_NORMSQ2);
  float*          normsq1 = (float*)(ws + OFF_NORMSQ1);
  unsigned*       s1key   = (unsigned*)(ws + OFF_S1KEY);
  unsigned*       s2key   = (unsigned*)(ws + OFF_S2KEY);
  float*          lr3n    = (float*)(ws + OFF_LR3N);
  float*          u3n     = (float*)(ws + OFF_U3N);
  unsigned short* lr3nbT  = (unsigned short*)(ws + OFF_LR3NBT);
  unsigned short* U2b     = (unsigned short*)(ws + OFF_U2B);
  unsigned short* U1b     = (unsigned short*)(ws + OFF_U1B);
  unsigned short* W1t     = (unsigned short*)(ws + OFF_W1T);
  unsigned short* W2t     = (unsigned short*)(ws + OFF_W2T);
  unsigned short* A2b     = (unsigned short*)(ws + OFF_A2);
  unsigned short* A1b     = (unsigned short*)(ws + OFF_A1);
  unsigned short* M2tb    = (unsigned short*)(ws + OFF_M2T);
  unsigned short* M1tb    = (unsigned short*)(ws + OFF_M1T);
  float*          R3t     = (float*)(ws + OFF_R3T);
  int*            R3arg   = (int*)(ws + OFF_R3ARG);
  float*          sclr    = (float*)(ws + OFF_SCLR);
  float*          scu3    = (float*)(ws + OFF_SCU3);
  float*          bw2     = (float*)(ws + OFF_BW2);
  float*          bw1     = (float*)(ws + OFF_BW1);
  float*          bl2     = (float*)(ws + OFF_BL2);
  float*          bl1     = (float*)(ws + OFF_BL1);
  float*          bb      = (float*)(ws + OFF_BB);
  float*          n2inv   = (float*)(ws + OFF_N2INV);
  float*          n1inv   = (float*)(ws + OFF_N1INV);

  hipMemsetAsync(d_ws, 0, ZERO_BYTES, stream);

  // unfold + normalize
  k_colnorm<<<1024, 256, 0, stream>>>(lrsr3, sclr);
  k_colnorm<<<1024, 256, 0, stream>>>(rsr3, scu3);
  k_pass2_dm<<<9216, 256, 0, stream>>>(lrsr3, sclr, lr3n);
  k_pass2_dm<<<9216, 256, 0, stream>>>(rsr3, scu3, u3n);
  k_pass2_md_bf<<<9216, 256, 0, stream>>>(lrsr3, sclr, lr3nbT);
  k_unfold_bf<<<18432, 256, 0, stream>>>(rsr2, U2b, 6, 1152, 4096 * 1152);
  k_unfold_bf<<<36864, 256, 0, stream>>>(rsr1, U1b, 7, 576, 16384 * 576);
  k_wtrans<<<10368, 256, 0, stream>>>(W1, W1t, 1152, 2304 * 1152);
  k_wtrans<<<5184, 256, 0, stream>>>(W2, W2t, 576, 2304 * 576);
  k_bw<<<5, 256, 0, stream>>>(W1, b1, bw2, 1152);
  k_bw<<<3, 256, 0, stream>>>(W2, b2, bw1, 576);
  k_bb<<<2, 256, 0, stream>>>(b1, b2, bb);
  k_bl<<<4, 256, 0, stream>>>(lr3n, b1, b2, bl2, bl1);

  // Gram matrices A = Wt @ Wt^T (symmetric) and M^T = lr3n^T @ W^T
  k_gemm<0><<<dim3(18, 18), 256, 0, stream>>>(W1t, W1t, A2b, 1152, 1152, 2304, nullptr, nullptr, nullptr, nullptr);
  k_gemm<0><<<dim3(9, 9), 256, 0, stream>>>(W2t, W2t, A1b, 576, 576, 2304, nullptr, nullptr, nullptr, nullptr);
  k_gemm<0><<<dim3(18, 16), 256, 0, stream>>>(lr3nbT, W1t, M2tb, 1024, 1152, 2304, nullptr, nullptr, nullptr, nullptr);
  k_gemm<0><<<dim3(9, 16), 256, 0, stream>>>(lr3nbT, W2t, M1tb, 1024, 576, 2304, nullptr, nullptr, nullptr, nullptr);
  // norms via Gram quadratic form (epilogue accumulates (U A) . U per row)
  k_gemm<1><<<dim3(18, 64), 256, 0, stream>>>(U2b, A2b, nullptr, 4096, 1152, 1152, nullptr, nullptr, normsq2, nullptr);
  k_gemm<1><<<dim3(9, 256), 256, 0, stream>>>(U1b, A1b, nullptr, 16384, 576, 576, nullptr, nullptr, normsq1, nullptr);
  k_normfin<<<4096, 128, 0, stream>>>(U2b, bw2, bb, 0, normsq2, n2inv, 1152);
  k_normfin<<<16384, 128, 0, stream>>>(U1b, bw1, bb, 1, normsq1, n1inv, 576);
  // score max: S = max_n (U@M^T + bl)/norm
  k_gemm<2><<<dim3(16, 64), 256, 0, stream>>>(U2b, M2tb, nullptr, 4096, 1024, 1152, bl2, n2inv, nullptr, s2key);
  k_gemm<2><<<dim3(16, 256), 256, 0, stream>>>(U1b, M1tb, nullptr, 16384, 1024, 576, bl1, n1inv, nullptr, s1key);

  // fp32 R3 path (argmax-critical)
  k_gemm_r3<<<dim3(16, 16), 256, 0, stream>>>(lr3n, u3n, R3t);
  k_argmax3<<<1024, 256, 0, stream>>>(R3t, out + 2048, R3arg);
  k_finS<<<4, 256, 0, stream>>>(s1key, s2key, out);

  // transfer: gather chosen columns and fold
  k_tfold3<<<1024, 256, 0, stream>>>(ref3, R3arg, out + 3072);
  k_tfold2<<<2048, 256, 0, stream>>>(ref2, R3arg, out + 265216);
  k_tfold1<<<4096, 256, 0, stream>>>(ref1, R3arg, out + 789504);
}

// Round 2
// 633.936 us; speedup vs baseline: 1.3296x; 1.3296x over previous
//
#include <hip/hip_runtime.h>

typedef short bf8 __attribute__((ext_vector_type(8)));
typedef float f32x4 __attribute__((ext_vector_type(4)));

static __device__ __forceinline__ unsigned short f2bf(float f) {
  unsigned u = __float_as_uint(f);
  unsigned r = u + 0x7FFFu + ((u >> 16) & 1u);
  return (unsigned short)(r >> 16);
}
static __device__ __forceinline__ float bf2f(unsigned short h) {
  return __uint_as_float(((unsigned)h) << 16);
}
static __device__ __forceinline__ unsigned fkey(float f) {
  unsigned u = __float_as_uint(f);
  return (u & 0x80000000u) ? ~u : (u | 0x80000000u);
}
static __device__ __forceinline__ float kdec(unsigned k) {
  unsigned u = (k & 0x80000000u) ? (k & 0x7FFFFFFFu) : ~k;
  return __uint_as_float(u);
}

// async global->LDS, 16B per lane. lds dest: wave-uniform base + lane*16.
static __device__ __forceinline__ void gload_lds16(const unsigned short* g, unsigned short* l) {
  __builtin_amdgcn_global_load_lds((const __attribute__((address_space(1))) void*)g,
                                   (__attribute__((address_space(3))) void*)l, 16, 0, 0);
}

// unfold(k=3,pad=1,stride=1) value: row d = (cc*3+ki)*3+kj, col m = i*S+j, src [C][S][S]
static __device__ __forceinline__ float uf3(const float* __restrict__ src, int lgS, int d, int m) {
  const int S = 1 << lgS;
  int cc = d / 9;
  int r9 = d - cc * 9;
  int ki = r9 / 3;
  int kj = r9 - ki * 3;
  int i = (m >> lgS) + ki - 1;
  int j = (m & (S - 1)) + kj - 1;
  if ((unsigned)i >= (unsigned)S || (unsigned)j >= (unsigned)S) return 0.f;
  return src[((size_t)cc << (2 * lgS)) + ((size_t)i << lgS) + j];
}

// ---------------- prep kernels ----------------

__global__ __launch_bounds__(256) void k_colnorm(const float* __restrict__ src, float* __restrict__ scale) {
  int m = blockIdx.x;
  float s = 0.f;
  for (int d = threadIdx.x; d < 2304; d += 256) {
    float v = uf3(src, 5, d, m);
    s += v * v;
  }
  __shared__ float red[256];
  red[threadIdx.x] = s; __syncthreads();
  for (int o = 128; o > 0; o >>= 1) { if (threadIdx.x < o) red[threadIdx.x] += red[threadIdx.x + o]; __syncthreads(); }
  if (threadIdx.x == 0) scale[m] = 1.f / fmaxf(sqrtf(red[0]), 1e-12f);
}

// normalized unfold, f32, layout [d][m] (d=2304, m=1024)
__global__ __launch_bounds__(256) void k_pass2_dm(const float* __restrict__ src, const float* __restrict__ scale, float* __restrict__ out) {
  int id = blockIdx.x * 256 + threadIdx.x;
  int d = id >> 10, m = id & 1023;
  out[id] = uf3(src, 5, d, m) * scale[m];
}
// normalized unfold, bf16, layout [m][d]
__global__ __launch_bounds__(256) void k_pass2_md_bf(const float* __restrict__ src, const float* __restrict__ scale, unsigned short* __restrict__ out) {
  int id = blockIdx.x * 256 + threadIdx.x;
  int m = id / 2304, d = id - m * 2304;
  out[id] = f2bf(uf3(src, 5, d, m) * scale[m]);
}
// plain unfold -> bf16, layout [n][c], with column padding (c >= CKreal -> 0)
__global__ __launch_bounds__(256) void k_unfold_bf(const float* __restrict__ src, unsigned short* __restrict__ out,
                                                   int lgS, int CKpad, int CKreal, int total) {
  int id = blockIdx.x * 256 + threadIdx.x;
  if (id >= total) return;
  int n = id / CKpad, c = id - n * CKpad;
  float v = (c < CKreal) ? uf3(src, lgS, c, n) : 0.f;
  out[id] = f2bf(v);
}
// W [2304][Cw] f32 -> Wt [Cw][2304] bf16
__global__ __launch_bounds__(256) void k_wtrans(const float* __restrict__ W, unsigned short* __restrict__ Wt, int Cw, int total) {
  int id = blockIdx.x * 256 + threadIdx.x;
  if (id >= total) return;
  int d = id / Cw, c = id - d * Cw;
  Wt[(size_t)c * 2304 + d] = f2bf(W[id]);
}
// bw[c] += sum_{d in chunk} b[d]*W[d][c]  (bw zero-initialized)
__global__ __launch_bounds__(256) void k_bw(const float* __restrict__ W, const float* __restrict__ b, float* __restrict__ bw,
                                            int CwPad, int CwReal) {
  int c = blockIdx.x * 256 + threadIdx.x;
  if (c >= CwReal) return;
  int d0 = blockIdx.y * 256;
  float s = 0.f;
  for (int d = d0; d < d0 + 256; ++d) s += b[d] * W[(size_t)d * CwReal + c];
  atomicAdd(&bw[c], s);
}
// bb[0]=||b1||^2, bb[1]=||b2||^2
__global__ __launch_bounds__(256) void k_bb(const float* __restrict__ b1, const float* __restrict__ b2, float* __restrict__ bb) {
  const float* b = blockIdx.x ? b2 : b1;
  float s = 0.f;
  for (int d = threadIdx.x; d < 2304; d += 256) s += b[d] * b[d];
  __shared__ float red[256];
  red[threadIdx.x] = s; __syncthreads();
  for (int o = 128; o > 0; o >>= 1) { if (threadIdx.x < o) red[threadIdx.x] += red[threadIdx.x + o]; __syncthreads(); }
  if (threadIdx.x == 0) bb[blockIdx.x] = red[0];
}
// bl2[m] += b1 . lr3n[chunk,m] ; bl1[m] += b2 . lr3n[chunk,m]   (zero-initialized)
__global__ __launch_bounds__(256) void k_bl(const float* __restrict__ lr3n, const float* __restrict__ b1, const float* __restrict__ b2,
                                            float* __restrict__ bl2, float* __restrict__ bl1) {
  int m = blockIdx.x * 256 + threadIdx.x;
  int d0 = blockIdx.y * 288;
  float s2 = 0.f, s1 = 0.f;
  for (int d = d0; d < d0 + 288; ++d) {
    float v = lr3n[(size_t)d * 1024 + m];
    s2 += b1[d] * v; s1 += b2[d] * v;
  }
  atomicAdd(&bl2[m], s2); atomicAdd(&bl1[m], s1);
}

// ---------------- bf16 MFMA GEMM (m97 structure): 128x128 tile, BK=64, 4 waves ----------------
// TN form: C[i][j] = sum_k A[i][k]*Bt[j][k].  M,N % 128 == 0, K % 64 == 0.
// EPI 0: store bf16 C[M][N]
// EPI 1: normsq[i] += sum_j C[i][j]*A[i][j]   (requires N==K; Bt = symmetric Gram)
// EPI 2: skey[j] = max_i fkey((C[i][j]+bl[j])*ninv[i])
template <int EPI>
__global__ __launch_bounds__(256) void k_gemm128(const unsigned short* __restrict__ A,
                                                 const unsigned short* __restrict__ Bt,
                                                 unsigned short* __restrict__ C,
                                                 int M, int N, int K,
                                                 const float* __restrict__ bl,
                                                 const float* __restrict__ ninv,
                                                 float* __restrict__ normsq,
                                                 unsigned* __restrict__ skey) {
  __shared__ __align__(16) unsigned short As[128 * 64];
  __shared__ __align__(16) unsigned short Bs[128 * 64];
  __shared__ unsigned colkey[128];
  const int tid = threadIdx.x;
  const int l = tid & 63;
  const int w = tid >> 6;          // wave 0..3
  const int wr = w >> 1, wc = w & 1;
  const int m0 = blockIdx.y * 128, n0 = blockIdx.x * 128;
  if (EPI == 2 && tid < 128) colkey[tid] = 0u;

  f32x4 acc[4][4] = {};

  // staging geometry: wave w stages rows [w*32, w*32+32) in 4 chunks of 8 rows;
  // lane l covers (row += l>>3, col = (l&7)*8); LDS chunk base is wave-uniform.
  const int srow = w * 32;
  const int lrow = l >> 3;
  const int lcol = (l & 7) * 8;
  const int mr = l & 15;           // fragment col / A-row lane
  const int kg = l >> 4;           // k-octet group

  for (int kb = 0; kb < K; kb += 64) {
    __syncthreads();
#pragma unroll
    for (int i = 0; i < 4; ++i) {
      int r = srow + i * 8;
      gload_lds16(A  + (size_t)(m0 + r + lrow) * K + kb + lcol, &As[r * 64]);
      gload_lds16(Bt + (size_t)(n0 + r + lrow) * K + kb + lcol, &Bs[r * 64]);
    }
    __syncthreads();  // drains vmcnt(0): staged tile visible
#pragma unroll
    for (int ks = 0; ks < 2; ++ks) {
      bf8 af[4], bv[4];
#pragma unroll
      for (int mi = 0; mi < 4; ++mi)
        af[mi] = *(const bf8*)&As[(wr * 64 + mi * 16 + mr) * 64 + ks * 32 + kg * 8];
#pragma unroll
      for (int ni = 0; ni < 4; ++ni)
        bv[ni] = *(const bf8*)&Bs[(wc * 64 + ni * 16 + mr) * 64 + ks * 32 + kg * 8];
#pragma unroll
      for (int mi = 0; mi < 4; ++mi)
#pragma unroll
        for (int ni = 0; ni < 4; ++ni)
          acc[mi][ni] = __builtin_amdgcn_mfma_f32_16x16x32_bf16(af[mi], bv[ni], acc[mi][ni], 0, 0, 0);
    }
  }

  // C/D frag layout: col = mr, row = kg*4 + e (within 16x16)
  const int gr0 = m0 + wr * 64;    // + mi*16 + kg*4 + e
  const int gc0 = n0 + wc * 64;    // + ni*16 + mr
  if (EPI == 0) {
#pragma unroll
    for (int mi = 0; mi < 4; ++mi)
#pragma unroll
      for (int ni = 0; ni < 4; ++ni)
#pragma unroll
        for (int e = 0; e < 4; ++e)
          C[(size_t)(gr0 + mi * 16 + kg * 4 + e) * (size_t)N + (gc0 + ni * 16 + mr)] = f2bf(acc[mi][ni][e]);
  } else if (EPI == 1) {
    float rp[4][4] = {};
#pragma unroll
    for (int mi = 0; mi < 4; ++mi)
#pragma unroll
      for (int ni = 0; ni < 4; ++ni) {
#pragma unroll
        for (int e = 0; e < 4; ++e)
          rp[mi][e] += acc[mi][ni][e] *
            bf2f(A[(size_t)(gr0 + mi * 16 + kg * 4 + e) * (size_t)K + (gc0 + ni * 16 + mr)]);
      }
#pragma unroll
    for (int off = 1; off < 16; off <<= 1)
#pragma unroll
      for (int mi = 0; mi < 4; ++mi)
#pragma unroll
        for (int e = 0; e < 4; ++e) rp[mi][e] += __shfl_xor(rp[mi][e], off);
    if (mr == 0) {
#pragma unroll
      for (int mi = 0; mi < 4; ++mi)
#pragma unroll
        for (int e = 0; e < 4; ++e)
          atomicAdd(&normsq[gr0 + mi * 16 + kg * 4 + e], rp[mi][e]);
    }
  } else {
    float nv[4][4];
#pragma unroll
    for (int mi = 0; mi < 4; ++mi)
#pragma unroll
      for (int e = 0; e < 4; ++e) nv[mi][e] = ninv[gr0 + mi * 16 + kg * 4 + e];
#pragma unroll
    for (int ni = 0; ni < 4; ++ni) {
      float blv = bl[gc0 + ni * 16 + mr];
      float mx = -3.0e38f;
#pragma unroll
      for (int mi = 0; mi < 4; ++mi)
#pragma unroll
        for (int e = 0; e < 4; ++e) mx = fmaxf(mx, (acc[mi][ni][e] + blv) * nv[mi][e]);
      atomicMax(&colkey[wc * 64 + ni * 16 + mr], fkey(mx));
    }
    __syncthreads();
    if (tid < 128) atomicMax(&skey[n0 + tid], colkey[tid]);
  }
}

// finalize norms: ninv[n] = 1/max(sqrt(max(normsq[n] + 2*bw.u_n + bb,0)),eps)
__global__ __launch_bounds__(128) void k_normfin(const unsigned short* __restrict__ U, const float* __restrict__ bw,
                                                 const float* __restrict__ bb, int which,
                                                 const float* __restrict__ normsq, float* __restrict__ ninv, int K) {
  int n = blockIdx.x;
  float s = 0.f;
  for (int c = threadIdx.x; c < K; c += 128) s += bw[c] * bf2f(U[(size_t)n * K + c]);
  __shared__ float red[128];
  red[threadIdx.x] = s; __syncthreads();
  for (int o = 64; o > 0; o >>= 1) { if (threadIdx.x < o) red[threadIdx.x] += red[threadIdx.x + o]; __syncthreads(); }
  if (threadIdx.x == 0) {
    float t = normsq[n] + 2.f * red[0] + bb[which];
    float nr = sqrtf(fmaxf(t, 0.f));
    ninv[n] = 1.f / fmaxf(nr, 1e-12f);
  }
}

// ---------------- fp32 R3^T GEMM, split-K=4: R3p[s][m][n] = sum_{d in slice s} lr3n[d][m]*u3n[d][n] ----------------
__global__ __launch_bounds__(256) void k_gemm_r3(const float* __restrict__ Apm, const float* __restrict__ Bpn,
                                                 float* __restrict__ R3p) {
  __shared__ float As[16][68];
  __shared__ float Bs[16][68];
  const int tid = threadIdx.x;
  const int tx = tid & 15, ty = tid >> 4;
  const int m0 = blockIdx.y * 64, n0 = blockIdx.x * 64;
  const int s = blockIdx.z;
  float acc[4][4] = {};
  for (int kb = s * 576; kb < (s + 1) * 576; kb += 16) {
    __syncthreads();
#pragma unroll
    for (int i = 0; i < 4; ++i) {
      int idx = tid + i * 256;
      int kk = idx >> 6, mm = idx & 63;
      As[kk][mm] = Apm[(size_t)(kb + kk) * 1024 + m0 + mm];
      Bs[kk][mm] = Bpn[(size_t)(kb + kk) * 1024 + n0 + mm];
    }
    __syncthreads();
#pragma unroll
    for (int kk = 0; kk < 16; ++kk) {
      float a[4], b[4];
#pragma unroll
      for (int e = 0; e < 4; ++e) { a[e] = As[kk][ty * 4 + e]; b[e] = Bs[kk][tx * 4 + e]; }
#pragma unroll
      for (int i = 0; i < 4; ++i)
#pragma unroll
        for (int j = 0; j < 4; ++j) acc[i][j] = fmaf(a[i], b[j], acc[i][j]);
    }
  }
  float* outp = R3p + (size_t)s * 1048576;
#pragma unroll
  for (int i = 0; i < 4; ++i)
#pragma unroll
    for (int j = 0; j < 4; ++j)
      outp[(size_t)(m0 + ty * 4 + i) * 1024 + (n0 + tx * 4 + j)] = acc[i][j];
}

// per-row max + first-argmax over n (sums the 4 split-K partials; deterministic)
__global__ __launch_bounds__(256) void k_argmax3(const float* __restrict__ R3p, float* __restrict__ s3, int* __restrict__ arg) {
  int m = blockIdx.x;
  const float* row = R3p + (size_t)m * 1024;
  float best = -3.0e38f; int bi = 0;
  for (int n = threadIdx.x; n < 1024; n += 256) {
    float v = row[n] + row[n + 1048576] + row[n + 2097152] + row[n + 3145728];
    if (v > best) { best = v; bi = n; }
  }
  __shared__ float bv[256]; __shared__ int bidx[256];
  bv[threadIdx.x] = best; bidx[threadIdx.x] = bi;
  __syncthreads();
  for (int o = 128; o > 0; o >>= 1) {
    if (threadIdx.x < o) {
      float ov = bv[threadIdx.x + o]; int oi = bidx[threadIdx.x + o];
      if (ov > bv[threadIdx.x] || (ov == bv[threadIdx.x] && oi < bidx[threadIdx.x])) {
        bv[threadIdx.x] = ov; bidx[threadIdx.x] = oi;
      }
    }
    __syncthreads();
  }
  if (threadIdx.x == 0) { s3[m] = bv[0]; arg[m] = bidx[0]; }
}

__global__ __launch_bounds__(256) void k_finS(const unsigned* __restrict__ k1, const unsigned* __restrict__ k2, float* __restrict__ out) {
  int t = blockIdx.x * 256 + threadIdx.x;
  if (t < 1024) { out[t] = kdec(k1[t]); out[1024 + t] = kdec(k2[t]); }
}

// ---------------- gather + fold ----------------
__global__ __launch_bounds__(256) void k_tfold3(const float* __restrict__ ref, const int* __restrict__ arg, float* __restrict__ out) {
  int id = blockIdx.x * 256 + threadIdx.x;
  int c = id >> 10, rem = id & 1023;
  int y = rem >> 5, x = rem & 31;
  float s = 0.f;
#pragma unroll
  for (int ki = 0; ki < 3; ++ki) {
    int i = y + 1 - ki;
    if ((unsigned)i >= 32u) continue;
#pragma unroll
    for (int kj = 0; kj < 3; ++kj) {
      int j = x + 1 - kj;
      if ((unsigned)j >= 32u) continue;
      int n2 = arg[i * 32 + j];
      int rr = (n2 >> 5) + ki - 1, cc = (n2 & 31) + kj - 1;
      if ((unsigned)rr < 32u && (unsigned)cc < 32u) s += ref[(size_t)c * 1024 + rr * 32 + cc];
    }
  }
  out[id] = s * (1.f / 9.f);
}
__global__ __launch_bounds__(256) void k_tfold2(const float* __restrict__ ref, const int* __restrict__ arg, float* __restrict__ out) {
  int id = blockIdx.x * 256 + threadIdx.x;
  int c = id >> 12, rem = id & 4095;
  int y = rem >> 6, x = rem & 63;
  float s = 0.f;
#pragma unroll
  for (int ki = 0; ki < 6; ++ki) {
    int t = y + 2 - ki;
    if (t < 0 || (t & 1)) continue;
    int i = t >> 1;
    if (i >= 32) continue;
#pragma unroll
    for (int kj = 0; kj < 6; ++kj) {
      int t2 = x + 2 - kj;
      if (t2 < 0 || (t2 & 1)) continue;
      int j = t2 >> 1;
      if (j >= 32) continue;
      int n2 = arg[i * 32 + j];
      int rr = (n2 >> 5) * 2 + ki - 2, cc = (n2 & 31) * 2 + kj - 2;
      if ((unsigned)rr < 64u && (unsigned)cc < 64u) s += ref[(size_t)c * 4096 + rr * 64 + cc];
    }
  }
  out[id] = s * (1.f / 9.f);
}
__global__ __launch_bounds__(256) void k_tfold1(const float* __restrict__ ref, const int* __restrict__ arg, float* __restrict__ out) {
  int id = blockIdx.x * 256 + threadIdx.x;
  int c = id >> 14, rem = id & 16383;
  int y = rem >> 7, x = rem & 127;
  float s = 0.f;
#pragma unroll
  for (int ki = 0; ki < 12; ++ki) {
    int t = y + 4 - ki;
    if (t < 0 || (t & 3)) continue;
    int i = t >> 2;
    if (i >= 32) continue;
#pragma unroll
    for (int kj = 0; kj < 12; ++kj) {
      int t2 = x + 4 - kj;
      if (t2 < 0 || (t2 & 3)) continue;
      int j = t2 >> 2;
      if (j >= 32) continue;
      int n2 = arg[i * 32 + j];
      int rr = (n2 >> 5) * 4 + ki - 4, cc = (n2 & 31) * 4 + kj - 4;
      if ((unsigned)rr < 128u && (unsigned)cc < 128u) s += ref[(size_t)c * 16384 + rr * 128 + cc];
    }
  }
  out[id] = s * (1.f / 9.f);
}

// ---------------- workspace layout (bytes) ----------------
// zero-initialized region (memset each launch):
static constexpr size_t OFF_NORMSQ2 = 0;              // 4096 f32
static constexpr size_t OFF_NORMSQ1 = 16384;          // 16384 f32
static constexpr size_t OFF_S1KEY   = 81920;          // 1024 u32
static constexpr size_t OFF_S2KEY   = 86016;          // 1024 u32
static constexpr size_t OFF_BW2     = 90112;          // 1152 f32
static constexpr size_t OFF_BW1     = 94720;          // 640 f32
static constexpr size_t OFF_BL2     = 97280;          // 1024 f32
static constexpr size_t OFF_BL1     = 101376;         // 1024 f32
static constexpr size_t ZERO_BYTES  = 105472;
// bulk:
static constexpr size_t OFF_LR3N    = 105472;                   // f32 [2304][1024]
static constexpr size_t OFF_U3N     = OFF_LR3N   + 9437184;     // f32 [2304][1024]
static constexpr size_t OFF_LR3NBT  = OFF_U3N    + 9437184;     // bf16 [1024][2304]
static constexpr size_t OFF_U2B     = OFF_LR3NBT + 4718592;     // bf16 [4096][1152]
static constexpr size_t OFF_U1B     = OFF_U2B    + 9437184;     // bf16 [16384][640] (cols 576+ zero)
static constexpr size_t OFF_W1T     = OFF_U1B    + 20971520;    // bf16 [1152][2304]
static constexpr size_t OFF_W2T     = OFF_W1T    + 5308416;     // bf16 [640][2304] (rows 576+ zero)
static constexpr size_t OFF_A2      = OFF_W2T    + 2949120;     // bf16 [1152][1152]
static constexpr size_t OFF_A1      = OFF_A2     + 2654208;     // bf16 [640][640]
static constexpr size_t OFF_M2T     = OFF_A1     + 819200;      // bf16 [1024][1152]
static constexpr size_t OFF_M1T     = OFF_M2T    + 2359296;     // bf16 [1024][640]
static constexpr size_t OFF_R3P     = OFF_M1T    + 1310720;     // f32 [4][1024][1024]
static constexpr size_t OFF_R3ARG   = OFF_R3P    + 16777216;    // int [1024]
static constexpr size_t OFF_SCLR    = OFF_R3ARG  + 4096;        // f32 [1024]
static constexpr size_t OFF_SCU3    = OFF_SCLR   + 4096;        // f32 [1024]
static constexpr size_t OFF_BB      = OFF_SCU3   + 4096;        // f32 [2]
static constexpr size_t OFF_N2INV   = OFF_BB     + 256;         // f32 [4096]
static constexpr size_t OFF_N1INV   = OFF_N2INV  + 16384;       // f32 [16384]

extern "C" void kernel_launch(void* const* d_in, const int* in_sizes, int n_in,
                              void* d_out, int out_size, void* d_ws, size_t ws_size,
                              hipStream_t stream) {
  (void)in_sizes; (void)n_in; (void)out_size; (void)ws_size;
  const float* lrsr3  = (const float*)d_in[0];
  const float* rsr1   = (const float*)d_in[1];
  const float* rsr2   = (const float*)d_in[2];
  const float* rsr3   = (const float*)d_in[3];
  const float* ref1   = (const float*)d_in[4];
  const float* ref2   = (const float*)d_in[5];
  const float* ref3   = (const float*)d_in[6];
  const float* W1     = (const float*)d_in[7];
  const float* b1     = (const float*)d_in[8];
  const float* W2     = (const float*)d_in[9];
  const float* b2     = (const float*)d_in[10];
  float* out = (float*)d_out;
  char* ws = (char*)d_ws;

  float*          normsq2 = (float*)(ws + OFF_NORMSQ2);
  float*          normsq1 = (float*)(ws + OFF_NORMSQ1);
  unsigned*       s1key   = (unsigned*)(ws + OFF_S1KEY);
  unsigned*       s2key   = (unsigned*)(ws + OFF_S2KEY);
  float*          bw2     = (float*)(ws + OFF_BW2);
  float*          bw1     = (float*)(ws + OFF_BW1);
  float*          bl2     = (float*)(ws + OFF_BL2);
  float*          bl1     = (float*)(ws + OFF_BL1);
  float*          lr3n    = (float*)(ws + OFF_LR3N);
  float*          u3n     = (float*)(ws + OFF_U3N);
  unsigned short* lr3nbT  = (unsigned short*)(ws + OFF_LR3NBT);
  unsigned short* U2b     = (unsigned short*)(ws + OFF_U2B);
  unsigned short* U1b     = (unsigned short*)(ws + OFF_U1B);
  unsigned short* W1t     = (unsigned short*)(ws + OFF_W1T);
  unsigned short* W2t     = (unsigned short*)(ws + OFF_W2T);
  unsigned short* A2b     = (unsigned short*)(ws + OFF_A2);
  unsigned short* A1b     = (unsigned short*)(ws + OFF_A1);
  unsigned short* M2tb    = (unsigned short*)(ws + OFF_M2T);
  unsigned short* M1tb    = (unsigned short*)(ws + OFF_M1T);
  float*          R3p     = (float*)(ws + OFF_R3P);
  int*            R3arg   = (int*)(ws + OFF_R3ARG);
  float*          sclr    = (float*)(ws + OFF_SCLR);
  float*          scu3    = (float*)(ws + OFF_SCU3);
  float*          bb      = (float*)(ws + OFF_BB);
  float*          n2inv   = (float*)(ws + OFF_N2INV);
  float*          n1inv   = (float*)(ws + OFF_N1INV);

  hipMemsetAsync(d_ws, 0, ZERO_BYTES, stream);
  // zero pad rows 576..639 of W2t
  hipMemsetAsync(ws + OFF_W2T + (size_t)576 * 2304 * 2, 0, (size_t)64 * 2304 * 2, stream);

  // unfold + normalize
  k_colnorm<<<1024, 256, 0, stream>>>(lrsr3, sclr);
  k_colnorm<<<1024, 256, 0, stream>>>(rsr3, scu3);
  k_pass2_dm<<<9216, 256, 0, stream>>>(lrsr3, sclr, lr3n);
  k_pass2_dm<<<9216, 256, 0, stream>>>(rsr3, scu3, u3n);
  k_pass2_md_bf<<<9216, 256, 0, stream>>>(lrsr3, sclr, lr3nbT);
  k_unfold_bf<<<18432, 256, 0, stream>>>(rsr2, U2b, 6, 1152, 1152, 4096 * 1152);
  k_unfold_bf<<<40960, 256, 0, stream>>>(rsr1, U1b, 7, 640, 576, 16384 * 640);
  k_wtrans<<<10368, 256, 0, stream>>>(W1, W1t, 1152, 2304 * 1152);
  k_wtrans<<<5184, 256, 0, stream>>>(W2, W2t, 576, 2304 * 576);
  k_bw<<<dim3(5, 9), 256, 0, stream>>>(W1, b1, bw2, 1152, 1152);
  k_bw<<<dim3(3, 9), 256, 0, stream>>>(W2, b2, bw1, 640, 576);
  k_bb<<<2, 256, 0, stream>>>(b1, b2, bb);
  k_bl<<<dim3(4, 8), 256, 0, stream>>>(lr3n, b1, b2, bl2, bl1);

  // Gram matrices A = Wt @ Wt^T (symmetric) and M^T = lr3n^T @ W^T
  k_gemm128<0><<<dim3(9, 9), 256, 0, stream>>>(W1t, W1t, A2b, 1152, 1152, 2304, nullptr, nullptr, nullptr, nullptr);
  k_gemm128<0><<<dim3(5, 5), 256, 0, stream>>>(W2t, W2t, A1b, 640, 640, 2304, nullptr, nullptr, nullptr, nullptr);
  k_gemm128<0><<<dim3(9, 8), 256, 0, stream>>>(lr3nbT, W1t, M2tb, 1024, 1152, 2304, nullptr, nullptr, nullptr, nullptr);
  k_gemm128<0><<<dim3(5, 8), 256, 0, stream>>>(lr3nbT, W2t, M1tb, 1024, 640, 2304, nullptr, nullptr, nullptr, nullptr);
  // norms via Gram quadratic form
  k_gemm128<1><<<dim3(9, 32), 256, 0, stream>>>(U2b, A2b, nullptr, 4096, 1152, 1152, nullptr, nullptr, normsq2, nullptr);
  k_gemm128<1><<<dim3(5, 128), 256, 0, stream>>>(U1b, A1b, nullptr, 16384, 640, 640, nullptr, nullptr, normsq1, nullptr);
  k_normfin<<<4096, 128, 0, stream>>>(U2b, bw2, bb, 0, normsq2, n2inv, 1152);
  k_normfin<<<16384, 128, 0, stream>>>(U1b, bw1, bb, 1, normsq1, n1inv, 640);
  // score max: S = max_n (U@M^T + bl)/norm
  k_gemm128<2><<<dim3(8, 32), 256, 0, stream>>>(U2b, M2tb, nullptr, 4096, 1024, 1152, bl2, n2inv, nullptr, s2key);
  k_gemm128<2><<<dim3(8, 128), 256, 0, stream>>>(U1b, M1tb, nullptr, 16384, 1024, 640, bl1, n1inv, nullptr, s1key);

  // fp32 R3 path (argmax-critical), split-K=4
  k_gemm_r3<<<dim3(16, 16, 4), 256, 0, stream>>>(lr3n, u3n, R3p);
  k_argmax3<<<1024, 256, 0, stream>>>(R3p, out + 2048, R3arg);
  k_finS<<<4, 256, 0, stream>>>(s1key, s2key, out);

  // transfer: gather chosen columns and fold
  k_tfold3<<<1024, 256, 0, stream>>>(ref3, R3arg, out + 3072);
  k_tfold2<<<2048, 256, 0, stream>>>(ref2, R3arg, out + 265216);
  k_tfold1<<<4096, 256, 0, stream>>>(ref1, R3arg, out + 789504);
}

// Round 3
// 570.461 us; speedup vs baseline: 1.4775x; 1.1113x over previous
//
#include <hip/hip_runtime.h>

typedef short bf8 __attribute__((ext_vector_type(8)));
typedef float f32x4 __attribute__((ext_vector_type(4)));

static __device__ __forceinline__ unsigned short f2bf(float f) {
  unsigned u = __float_as_uint(f);
  unsigned r = u + 0x7FFFu + ((u >> 16) & 1u);
  return (unsigned short)(r >> 16);
}
static __device__ __forceinline__ float bf2f(unsigned short h) {
  return __uint_as_float(((unsigned)h) << 16);
}
static __device__ __forceinline__ unsigned fkey(float f) {
  unsigned u = __float_as_uint(f);
  return (u & 0x80000000u) ? ~u : (u | 0x80000000u);
}
static __device__ __forceinline__ float kdec(unsigned k) {
  unsigned u = (k & 0x80000000u) ? (k & 0x7FFFFFFFu) : ~k;
  return __uint_as_float(u);
}

// async global->LDS, 16B per lane. lds dest: wave-uniform base + lane*16.
static __device__ __forceinline__ void gload_lds16(const unsigned short* g, unsigned short* l) {
  __builtin_amdgcn_global_load_lds((const __attribute__((address_space(1))) void*)g,
                                   (__attribute__((address_space(3))) void*)l, 16, 0, 0);
}

// unfold(k=3,pad=1,stride=1) value: row d = (cc*3+ki)*3+kj, col m = i*S+j, src [C][S][S]
static __device__ __forceinline__ float uf3(const float* __restrict__ src, int lgS, int d, int m) {
  const int S = 1 << lgS;
  int cc = d / 9;
  int r9 = d - cc * 9;
  int ki = r9 / 3;
  int kj = r9 - ki * 3;
  int i = (m >> lgS) + ki - 1;
  int j = (m & (S - 1)) + kj - 1;
  if ((unsigned)i >= (unsigned)S || (unsigned)j >= (unsigned)S) return 0.f;
  return src[((size_t)cc << (2 * lgS)) + ((size_t)i << lgS) + j];
}

// ---------------- prep kernels ----------------

// per-column 1/max(||col||,eps) of unfold(src,3,1,1), S=32, CKK=2304
__global__ __launch_bounds__(256) void k_colnorm(const float* __restrict__ src, float* __restrict__ scale) {
  int m = blockIdx.x;
  float s = 0.f;
  for (int d = threadIdx.x; d < 2304; d += 256) {
    float v = uf3(src, 5, d, m);
    s += v * v;
  }
  __shared__ float red[256];
  red[threadIdx.x] = s; __syncthreads();
  for (int o = 128; o > 0; o >>= 1) { if (threadIdx.x < o) red[threadIdx.x] += red[threadIdx.x + o]; __syncthreads(); }
  if (threadIdx.x == 0) scale[m] = 1.f / fmaxf(sqrtf(red[0]), 1e-12f);
}

// colnorm of lrsr3 + bias dots: scale[m]=1/max(||col||,eps); bl2[m]=(b1.col)*scale; bl1[m]=(b2.col)*scale
__global__ __launch_bounds__(256) void k_colnorm_bl(const float* __restrict__ src,
                                                    const float* __restrict__ b1, const float* __restrict__ b2,
                                                    float* __restrict__ scale,
                                                    float* __restrict__ bl2, float* __restrict__ bl1) {
  int m = blockIdx.x;
  float s = 0.f, d1 = 0.f, d2 = 0.f;
  for (int d = threadIdx.x; d < 2304; d += 256) {
    float v = uf3(src, 5, d, m);
    s += v * v; d1 += b1[d] * v; d2 += b2[d] * v;
  }
  __shared__ float r0[256], r1[256], r2[256];
  r0[threadIdx.x] = s; r1[threadIdx.x] = d1; r2[threadIdx.x] = d2;
  __syncthreads();
  for (int o = 128; o > 0; o >>= 1) {
    if (threadIdx.x < o) {
      r0[threadIdx.x] += r0[threadIdx.x + o];
      r1[threadIdx.x] += r1[threadIdx.x + o];
      r2[threadIdx.x] += r2[threadIdx.x + o];
    }
    __syncthreads();
  }
  if (threadIdx.x == 0) {
    float sc = 1.f / fmaxf(sqrtf(r0[0]), 1e-12f);
    scale[m] = sc; bl2[m] = r1[0] * sc; bl1[m] = r2[0] * sc;
  }
}

// normalized unfold, bf16, layout [m][d]
__global__ __launch_bounds__(256) void k_pass2_md_bf(const float* __restrict__ src, const float* __restrict__ scale, unsigned short* __restrict__ out) {
  int id = blockIdx.x * 256 + threadIdx.x;
  int m = id / 2304, d = id - m * 2304;
  out[id] = f2bf(uf3(src, 5, d, m) * scale[m]);
}
// plain unfold -> bf16, layout [n][c], with column padding (c >= CKreal -> 0)
__global__ __launch_bounds__(256) void k_unfold_bf(const float* __restrict__ src, unsigned short* __restrict__ out,
                                                   int lgS, int CKpad, int CKreal, int total) {
  int id = blockIdx.x * 256 + threadIdx.x;
  if (id >= total) return;
  int n = id / CKpad, c = id - n * CKpad;
  float v = (c < CKreal) ? uf3(src, lgS, c, n) : 0.f;
  out[id] = f2bf(v);
}
// W [2304][Cw] f32 -> Wt [Cw][2304] bf16
__global__ __launch_bounds__(256) void k_wtrans(const float* __restrict__ W, unsigned short* __restrict__ Wt, int Cw, int total) {
  int id = blockIdx.x * 256 + threadIdx.x;
  if (id >= total) return;
  int d = id / Cw, c = id - d * Cw;
  Wt[(size_t)c * 2304 + d] = f2bf(W[id]);
}
// bw[c] += sum_{d in chunk} b[d]*W[d][c]  (bw zero-initialized)
__global__ __launch_bounds__(256) void k_bw(const float* __restrict__ W, const float* __restrict__ b, float* __restrict__ bw,
                                            int CwPad, int CwReal) {
  int c = blockIdx.x * 256 + threadIdx.x;
  if (c >= CwReal) return;
  int d0 = blockIdx.y * 256;
  float s = 0.f;
  for (int d = d0; d < d0 + 256; ++d) s += b[d] * W[(size_t)d * CwReal + c];
  atomicAdd(&bw[c], s);
}
// bb[0]=||b1||^2, bb[1]=||b2||^2
__global__ __launch_bounds__(256) void k_bb(const float* __restrict__ b1, const float* __restrict__ b2, float* __restrict__ bb) {
  const float* b = blockIdx.x ? b2 : b1;
  float s = 0.f;
  for (int d = threadIdx.x; d < 2304; d += 256) s += b[d] * b[d];
  __shared__ float red[256];
  red[threadIdx.x] = s; __syncthreads();
  for (int o = 128; o > 0; o >>= 1) { if (threadIdx.x < o) red[threadIdx.x] += red[threadIdx.x + o]; __syncthreads(); }
  if (threadIdx.x == 0) bb[blockIdx.x] = red[0];
}

// ---------------- bf16 MFMA GEMM (m97 structure): 128x128 tile, BK=64, 4 waves ----------------
// TN form: C[i][j] = sum_k A[i][k]*Bt[j][k].  M,N % 128 == 0, K % 64 == 0.
// EPI 0: store bf16 C[M][N]
// EPI 1: normsq[i] += sum_j C[i][j]*A[i][j]   (requires N==K; Bt = symmetric Gram)
// EPI 2: skey[j] = max_i fkey((C[i][j]+bl[j])*ninv[i])
template <int EPI>
__global__ __launch_bounds__(256) void k_gemm128(const unsigned short* __restrict__ A,
                                                 const unsigned short* __restrict__ Bt,
                                                 unsigned short* __restrict__ C,
                                                 int M, int N, int K,
                                                 const float* __restrict__ bl,
                                                 const float* __restrict__ ninv,
                                                 float* __restrict__ normsq,
                                                 unsigned* __restrict__ skey) {
  __shared__ __align__(16) unsigned short As[128 * 64];
  __shared__ __align__(16) unsigned short Bs[128 * 64];
  __shared__ unsigned colkey[128];
  const int tid = threadIdx.x;
  const int l = tid & 63;
  const int w = tid >> 6;          // wave 0..3
  const int wr = w >> 1, wc = w & 1;
  const int m0 = blockIdx.y * 128, n0 = blockIdx.x * 128;
  if (EPI == 2 && tid < 128) colkey[tid] = 0u;

  f32x4 acc[4][4] = {};

  // staging geometry: wave w stages rows [w*32, w*32+32) in 4 chunks of 8 rows;
  // lane l covers (row += l>>3, col = (l&7)*8); LDS chunk base is wave-uniform.
  const int srow = w * 32;
  const int lrow = l >> 3;
  const int lcol = (l & 7) * 8;
  const int mr = l & 15;           // fragment col / A-row lane
  const int kg = l >> 4;           // k-octet group

  for (int kb = 0; kb < K; kb += 64) {
    __syncthreads();
#pragma unroll
    for (int i = 0; i < 4; ++i) {
      int r = srow + i * 8;
      gload_lds16(A  + (size_t)(m0 + r + lrow) * K + kb + lcol, &As[r * 64]);
      gload_lds16(Bt + (size_t)(n0 + r + lrow) * K + kb + lcol, &Bs[r * 64]);
    }
    __syncthreads();  // drains vmcnt(0): staged tile visible
#pragma unroll
    for (int ks = 0; ks < 2; ++ks) {
      bf8 af[4], bv[4];
#pragma unroll
      for (int mi = 0; mi < 4; ++mi)
        af[mi] = *(const bf8*)&As[(wr * 64 + mi * 16 + mr) * 64 + ks * 32 + kg * 8];
#pragma unroll
      for (int ni = 0; ni < 4; ++ni)
        bv[ni] = *(const bf8*)&Bs[(wc * 64 + ni * 16 + mr) * 64 + ks * 32 + kg * 8];
#pragma unroll
      for (int mi = 0; mi < 4; ++mi)
#pragma unroll
        for (int ni = 0; ni < 4; ++ni)
          acc[mi][ni] = __builtin_amdgcn_mfma_f32_16x16x32_bf16(af[mi], bv[ni], acc[mi][ni], 0, 0, 0);
    }
  }

  // C/D frag layout: col = mr, row = kg*4 + e (within 16x16)
  const int gr0 = m0 + wr * 64;    // + mi*16 + kg*4 + e
  const int gc0 = n0 + wc * 64;    // + ni*16 + mr
  if (EPI == 0) {
#pragma unroll
    for (int mi = 0; mi < 4; ++mi)
#pragma unroll
      for (int ni = 0; ni < 4; ++ni)
#pragma unroll
        for (int e = 0; e < 4; ++e)
          C[(size_t)(gr0 + mi * 16 + kg * 4 + e) * (size_t)N + (gc0 + ni * 16 + mr)] = f2bf(acc[mi][ni][e]);
  } else if (EPI == 1) {
    float rp[4][4] = {};
#pragma unroll
    for (int mi = 0; mi < 4; ++mi)
#pragma unroll
      for (int ni = 0; ni < 4; ++ni) {
#pragma unroll
        for (int e = 0; e < 4; ++e)
          rp[mi][e] += acc[mi][ni][e] *
            bf2f(A[(size_t)(gr0 + mi * 16 + kg * 4 + e) * (size_t)K + (gc0 + ni * 16 + mr)]);
      }
#pragma unroll
    for (int off = 1; off < 16; off <<= 1)
#pragma unroll
      for (int mi = 0; mi < 4; ++mi)
#pragma unroll
        for (int e = 0; e < 4; ++e) rp[mi][e] += __shfl_xor(rp[mi][e], off);
    if (mr == 0) {
#pragma unroll
      for (int mi = 0; mi < 4; ++mi)
#pragma unroll
        for (int e = 0; e < 4; ++e)
          atomicAdd(&normsq[gr0 + mi * 16 + kg * 4 + e], rp[mi][e]);
    }
  } else {
    float nv[4][4];
#pragma unroll
    for (int mi = 0; mi < 4; ++mi)
#pragma unroll
      for (int e = 0; e < 4; ++e) nv[mi][e] = ninv[gr0 + mi * 16 + kg * 4 + e];
#pragma unroll
    for (int ni = 0; ni < 4; ++ni) {
      float blv = bl[gc0 + ni * 16 + mr];
      float mx = -3.0e38f;
#pragma unroll
      for (int mi = 0; mi < 4; ++mi)
#pragma unroll
        for (int e = 0; e < 4; ++e) mx = fmaxf(mx, (acc[mi][ni][e] + blv) * nv[mi][e]);
      atomicMax(&colkey[wc * 64 + ni * 16 + mr], fkey(mx));
    }
    __syncthreads();
    if (tid < 128) atomicMax(&skey[n0 + tid], colkey[tid]);
  }
}

// finalize norms: ninv[n] = 1/max(sqrt(max(normsq[n] + 2*bw.u_n + bb,0)),eps)
__global__ __launch_bounds__(128) void k_normfin(const unsigned short* __restrict__ U, const float* __restrict__ bw,
                                                 const float* __restrict__ bb, int which,
                                                 const float* __restrict__ normsq, float* __restrict__ ninv, int K) {
  int n = blockIdx.x;
  float s = 0.f;
  for (int c = threadIdx.x; c < K; c += 128) s += bw[c] * bf2f(U[(size_t)n * K + c]);
  __shared__ float red[128];
  red[threadIdx.x] = s; __syncthreads();
  for (int o = 64; o > 0; o >>= 1) { if (threadIdx.x < o) red[threadIdx.x] += red[threadIdx.x + o]; __syncthreads(); }
  if (threadIdx.x == 0) {
    float t = normsq[n] + 2.f * red[0] + bb[which];
    float nr = sqrtf(fmaxf(t, 0.f));
    ninv[n] = 1.f / fmaxf(nr, 1e-12f);
  }
}

// ---------------- fp32 pixel Gram: G2[m][n] = sum_c L[c][m]*R[c][n], 1024x1024, K=256 ----------------
__global__ __launch_bounds__(256) void k_pixgram(const float* __restrict__ L, const float* __restrict__ R,
                                                 float* __restrict__ G2) {
  __shared__ float As[16][32];  // [k][m]
  __shared__ float Bs[16][32];  // [k][n]
  const int tid = threadIdx.x;
  const int tx = tid & 15, ty = tid >> 4;
  const int m0 = blockIdx.y * 32, n0 = blockIdx.x * 32;
  float acc[2][2] = {};
  for (int kb = 0; kb < 256; kb += 16) {
    __syncthreads();
    {
      int kk = tid >> 5, mm = tid & 31;
      As[kk][mm] = L[(size_t)(kb + kk) * 1024 + m0 + mm];
      Bs[kk][mm] = R[(size_t)(kb + kk) * 1024 + n0 + mm];
      int e2 = tid + 256; int kk2 = e2 >> 5, mm2 = e2 & 31;
      As[kk2][mm2] = L[(size_t)(kb + kk2) * 1024 + m0 + mm2];
      Bs[kk2][mm2] = R[(size_t)(kb + kk2) * 1024 + n0 + mm2];
    }
    __syncthreads();
#pragma unroll
    for (int kk = 0; kk < 16; ++kk) {
      float a0 = As[kk][ty * 2], a1 = As[kk][ty * 2 + 1];
      float b0 = Bs[kk][tx * 2], b1 = Bs[kk][tx * 2 + 1];
      acc[0][0] = fmaf(a0, b0, acc[0][0]); acc[0][1] = fmaf(a0, b1, acc[0][1]);
      acc[1][0] = fmaf(a1, b0, acc[1][0]); acc[1][1] = fmaf(a1, b1, acc[1][1]);
    }
  }
#pragma unroll
  for (int i = 0; i < 2; ++i)
#pragma unroll
    for (int j = 0; j < 2; ++j)
      G2[(size_t)(m0 + ty * 2 + i) * 1024 + (n0 + tx * 2 + j)] = acc[i][j];
}

// ---------------- R3 max/argmax from pixel Gram via masked 9-point diagonal-shift sum ----------------
// R3[n][m] = (sum_{dy,dx} mask * G2[m+off][n+off]) * scu3[n] * sclr[m], off = dy*32+dx.
// Output: s3[m] = max_n, arg[m] = first argmax_n.
__global__ __launch_bounds__(256) void k_r3max(const float* __restrict__ G2, const float* __restrict__ scu3,
                                               const float* __restrict__ sclr,
                                               float* __restrict__ s3, int* __restrict__ arg) {
  const int m = blockIdx.x;
  const int mi = m >> 5, mj = m & 31;
  float best = -3.0e38f; int bi = 0;
  for (int n = threadIdx.x; n < 1024; n += 256) {
    const int ni = n >> 5, nj = n & 31;
    float raw = 0.f;
#pragma unroll
    for (int dy = -1; dy <= 1; ++dy) {
#pragma unroll
      for (int dx = -1; dx <= 1; ++dx) {
        bool vm = ((unsigned)(mi + dy) < 32u) && ((unsigned)(mj + dx) < 32u);
        bool vn = ((unsigned)(ni + dy) < 32u) && ((unsigned)(nj + dx) < 32u);
        if (vm && vn) {
          int off = dy * 32 + dx;
          raw += G2[(size_t)(m + off) * 1024 + (n + off)];
        }
      }
    }
    float v = raw * scu3[n];
    if (v > best) { best = v; bi = n; }
  }
  __shared__ float bv[256]; __shared__ int bidx[256];
  bv[threadIdx.x] = best; bidx[threadIdx.x] = bi;
  __syncthreads();
  for (int o = 128; o > 0; o >>= 1) {
    if (threadIdx.x < o) {
      float ov = bv[threadIdx.x + o]; int oi = bidx[threadIdx.x + o];
      if (ov > bv[threadIdx.x] || (ov == bv[threadIdx.x] && oi < bidx[threadIdx.x])) {
        bv[threadIdx.x] = ov; bidx[threadIdx.x] = oi;
      }
    }
    __syncthreads();
  }
  if (threadIdx.x == 0) { s3[m] = bv[0] * sclr[m]; arg[m] = bidx[0]; }
}

__global__ __launch_bounds__(256) void k_finS(const unsigned* __restrict__ k1, const unsigned* __restrict__ k2, float* __restrict__ out) {
  int t = blockIdx.x * 256 + threadIdx.x;
  if (t < 1024) { out[t] = kdec(k1[t]); out[1024 + t] = kdec(k2[t]); }
}

// ---------------- gather + fold ----------------
__global__ __launch_bounds__(256) void k_tfold3(const float* __restrict__ ref, const int* __restrict__ arg, float* __restrict__ out) {
  int id = blockIdx.x * 256 + threadIdx.x;
  int c = id >> 10, rem = id & 1023;
  int y = rem >> 5, x = rem & 31;
  float s = 0.f;
#pragma unroll
  for (int ki = 0; ki < 3; ++ki) {
    int i = y + 1 - ki;
    if ((unsigned)i >= 32u) continue;
#pragma unroll
    for (int kj = 0; kj < 3; ++kj) {
      int j = x + 1 - kj;
      if ((unsigned)j >= 32u) continue;
      int n2 = arg[i * 32 + j];
      int rr = (n2 >> 5) + ki - 1, cc = (n2 & 31) + kj - 1;
      if ((unsigned)rr < 32u && (unsigned)cc < 32u) s += ref[(size_t)c * 1024 + rr * 32 + cc];
    }
  }
  out[id] = s * (1.f / 9.f);
}
__global__ __launch_bounds__(256) void k_tfold2(const float* __restrict__ ref, const int* __restrict__ arg, float* __restrict__ out) {
  int id = blockIdx.x * 256 + threadIdx.x;
  int c = id >> 12, rem = id & 4095;
  int y = rem >> 6, x = rem & 63;
  float s = 0.f;
#pragma unroll
  for (int ki = 0; ki < 6; ++ki) {
    int t = y + 2 - ki;
    if (t < 0 || (t & 1)) continue;
    int i = t >> 1;
    if (i >= 32) continue;
#pragma unroll
    for (int kj = 0; kj < 6; ++kj) {
      int t2 = x + 2 - kj;
      if (t2 < 0 || (t2 & 1)) continue;
      int j = t2 >> 1;
      if (j >= 32) continue;
      int n2 = arg[i * 32 + j];
      int rr = (n2 >> 5) * 2 + ki - 2, cc = (n2 & 31) * 2 + kj - 2;
      if ((unsigned)rr < 64u && (unsigned)cc < 64u) s += ref[(size_t)c * 4096 + rr * 64 + cc];
    }
  }
  out[id] = s * (1.f / 9.f);
}
__global__ __launch_bounds__(256) void k_tfold1(const float* __restrict__ ref, const int* __restrict__ arg, float* __restrict__ out) {
  int id = blockIdx.x * 256 + threadIdx.x;
  int c = id >> 14, rem = id & 16383;
  int y = rem >> 7, x = rem & 127;
  float s = 0.f;
#pragma unroll
  for (int ki = 0; ki < 12; ++ki) {
    int t = y + 4 - ki;
    if (t < 0 || (t & 3)) continue;
    int i = t >> 2;
    if (i >= 32) continue;
#pragma unroll
    for (int kj = 0; kj < 12; ++kj) {
      int t2 = x + 4 - kj;
      if (t2 < 0 || (t2 & 3)) continue;
      int j = t2 >> 2;
      if (j >= 32) continue;
      int n2 = arg[i * 32 + j];
      int rr = (n2 >> 5) * 4 + ki - 4, cc = (n2 & 31) * 4 + kj - 4;
      if ((unsigned)rr < 128u && (unsigned)cc < 128u) s += ref[(size_t)c * 16384 + rr * 128 + cc];
    }
  }
  out[id] = s * (1.f / 9.f);
}

// ---------------- workspace layout (bytes) ----------------
// zero-initialized region (memset each launch):
static constexpr size_t OFF_NORMSQ2 = 0;              // 4096 f32
static constexpr size_t OFF_NORMSQ1 = 16384;          // 16384 f32
static constexpr size_t OFF_S1KEY   = 81920;          // 1024 u32
static constexpr size_t OFF_S2KEY   = 86016;          // 1024 u32
static constexpr size_t OFF_BW2     = 90112;          // 1152 f32
static constexpr size_t OFF_BW1     = 94720;          // 640 f32
static constexpr size_t ZERO_BYTES  = 97280;
// non-zeroed:
static constexpr size_t OFF_BL2     = 97280;                    // f32 [1024] (written directly)
static constexpr size_t OFF_BL1     = 101376;                   // f32 [1024]
static constexpr size_t OFF_LR3NBT  = 105472;                   // bf16 [1024][2304]
static constexpr size_t OFF_U2B     = OFF_LR3NBT + 4718592;     // bf16 [4096][1152]
static constexpr size_t OFF_U1B     = OFF_U2B    + 9437184;     // bf16 [16384][640] (cols 576+ zero)
static constexpr size_t OFF_W1T     = OFF_U1B    + 20971520;    // bf16 [1152][2304]
static constexpr size_t OFF_W2T     = OFF_W1T    + 5308416;     // bf16 [640][2304] (rows 576+ zero)
static constexpr size_t OFF_A2      = OFF_W2T    + 2949120;     // bf16 [1152][1152]
static constexpr size_t OFF_A1      = OFF_A2     + 2654208;     // bf16 [640][640]
static constexpr size_t OFF_M2T     = OFF_A1     + 819200;      // bf16 [1024][1152]
static constexpr size_t OFF_M1T     = OFF_M2T    + 2359296;     // bf16 [1024][640]
static constexpr size_t OFF_G2      = OFF_M1T    + 1310720;     // f32 [1024][1024]
static constexpr size_t OFF_R3ARG   = OFF_G2     + 4194304;     // int [1024]
static constexpr size_t OFF_SCLR    = OFF_R3ARG  + 4096;        // f32 [1024]
static constexpr size_t OFF_SCU3    = OFF_SCLR   + 4096;        // f32 [1024]
static constexpr size_t OFF_BB      = OFF_SCU3   + 4096;        // f32 [2]
static constexpr size_t OFF_N2INV   = OFF_BB     + 256;         // f32 [4096]
static constexpr size_t OFF_N1INV   = OFF_N2INV  + 16384;       // f32 [16384]

extern "C" void kernel_launch(void* const* d_in, const int* in_sizes, int n_in,
                              void* d_out, int out_size, void* d_ws, size_t ws_size,
                              hipStream_t stream) {
  (void)in_sizes; (void)n_in; (void)out_size; (void)ws_size;
  const float* lrsr3  = (const float*)d_in[0];
  const float* rsr1   = (const float*)d_in[1];
  const float* rsr2   = (const float*)d_in[2];
  const float* rsr3   = (const float*)d_in[3];
  const float* ref1   = (const float*)d_in[4];
  const float* ref2   = (const float*)d_in[5];
  const float* ref3   = (const float*)d_in[6];
  const float* W1     = (const float*)d_in[7];
  const float* b1     = (const float*)d_in[8];
  const float* W2     = (const float*)d_in[9];
  const float* b2     = (const float*)d_in[10];
  float* out = (float*)d_out;
  char* ws = (char*)d_ws;

  float*          normsq2 = (float*)(ws + OFF_NORMSQ2);
  float*          normsq1 = (float*)(ws + OFF_NORMSQ1);
  unsigned*       s1key   = (unsigned*)(ws + OFF_S1KEY);
  unsigned*       s2key   = (unsigned*)(ws + OFF_S2KEY);
  float*          bw2     = (float*)(ws + OFF_BW2);
  float*          bw1     = (float*)(ws + OFF_BW1);
  float*          bl2     = (float*)(ws + OFF_BL2);
  float*          bl1     = (float*)(ws + OFF_BL1);
  unsigned short* lr3nbT  = (unsigned short*)(ws + OFF_LR3NBT);
  unsigned short* U2b     = (unsigned short*)(ws + OFF_U2B);
  unsigned short* U1b     = (unsigned short*)(ws + OFF_U1B);
  unsigned short* W1t     = (unsigned short*)(ws + OFF_W1T);
  unsigned short* W2t     = (unsigned short*)(ws + OFF_W2T);
  unsigned short* A2b     = (unsigned short*)(ws + OFF_A2);
  unsigned short* A1b     = (unsigned short*)(ws + OFF_A1);
  unsigned short* M2tb    = (unsigned short*)(ws + OFF_M2T);
  unsigned short* M1tb    = (unsigned short*)(ws + OFF_M1T);
  float*          G2      = (float*)(ws + OFF_G2);
  int*            R3arg   = (int*)(ws + OFF_R3ARG);
  float*          sclr    = (float*)(ws + OFF_SCLR);
  float*          scu3    = (float*)(ws + OFF_SCU3);
  float*          bb      = (float*)(ws + OFF_BB);
  float*          n2inv   = (float*)(ws + OFF_N2INV);
  float*          n1inv   = (float*)(ws + OFF_N1INV);

  hipMemsetAsync(d_ws, 0, ZERO_BYTES, stream);
  // zero pad rows 576..639 of W2t
  hipMemsetAsync(ws + OFF_W2T + (size_t)576 * 2304 * 2, 0, (size_t)64 * 2304 * 2, stream);

  // norms + bias dots + pixel Gram (R3 path, all fp32, no unfold materialization)
  k_colnorm_bl<<<1024, 256, 0, stream>>>(lrsr3, b1, b2, sclr, bl2, bl1);
  k_colnorm<<<1024, 256, 0, stream>>>(rsr3, scu3);
  k_pixgram<<<dim3(32, 32), 256, 0, stream>>>(lrsr3, rsr3, G2);
  k_r3max<<<1024, 256, 0, stream>>>(G2, scu3, sclr, out + 2048, R3arg);

  // unfolds / transposes for the bf16 score paths
  k_pass2_md_bf<<<9216, 256, 0, stream>>>(lrsr3, sclr, lr3nbT);
  k_unfold_bf<<<18432, 256, 0, stream>>>(rsr2, U2b, 6, 1152, 1152, 4096 * 1152);
  k_unfold_bf<<<40960, 256, 0, stream>>>(rsr1, U1b, 7, 640, 576, 16384 * 640);
  k_wtrans<<<10368, 256, 0, stream>>>(W1, W1t, 1152, 2304 * 1152);
  k_wtrans<<<5184, 256, 0, stream>>>(W2, W2t, 576, 2304 * 576);
  k_bw<<<dim3(5, 9), 256, 0, stream>>>(W1, b1, bw2, 1152, 1152);
  k_bw<<<dim3(3, 9), 256, 0, stream>>>(W2, b2, bw1, 640, 576);
  k_bb<<<2, 256, 0, stream>>>(b1, b2, bb);

  // Gram matrices A = Wt @ Wt^T (symmetric) and M^T = lr3n^T @ W^T
  k_gemm128<0><<<dim3(9, 9), 256, 0, stream>>>(W1t, W1t, A2b, 1152, 1152, 2304, nullptr, nullptr, nullptr, nullptr);
  k_gemm128<0><<<dim3(5, 5), 256, 0, stream>>>(W2t, W2t, A1b, 640, 640, 2304, nullptr, nullptr, nullptr, nullptr);
  k_gemm128<0><<<dim3(9, 8), 256, 0, stream>>>(lr3nbT, W1t, M2tb, 1024, 1152, 2304, nullptr, nullptr, nullptr, nullptr);
  k_gemm128<0><<<dim3(5, 8), 256, 0, stream>>>(lr3nbT, W2t, M1tb, 1024, 640, 2304, nullptr, nullptr, nullptr, nullptr);
  // norms via Gram quadratic form
  k_gemm128<1><<<dim3(9, 32), 256, 0, stream>>>(U2b, A2b, nullptr, 4096, 1152, 1152, nullptr, nullptr, normsq2, nullptr);
  k_gemm128<1><<<dim3(5, 128), 256, 0, stream>>>(U1b, A1b, nullptr, 16384, 640, 640, nullptr, nullptr, normsq1, nullptr);
  k_normfin<<<4096, 128, 0, stream>>>(U2b, bw2, bb, 0, normsq2, n2inv, 1152);
  k_normfin<<<16384, 128, 0, stream>>>(U1b, bw1, bb, 1, normsq1, n1inv, 640);
  // score max: S = max_n (U@M^T + bl)/norm
  k_gemm128<2><<<dim3(8, 32), 256, 0, stream>>>(U2b, M2tb, nullptr, 4096, 1024, 1152, bl2, n2inv, nullptr, s2key);
  k_gemm128<2><<<dim3(8, 128), 256, 0, stream>>>(U1b, M1tb, nullptr, 16384, 1024, 640, bl1, n1inv, nullptr, s1key);

  k_finS<<<4, 256, 0, stream>>>(s1key, s2key, out);

  // transfer: gather chosen columns and fold
  k_tfold3<<<1024, 256, 0, stream>>>(ref3, R3arg, out + 3072);
  k_tfold2<<<2048, 256, 0, stream>>>(ref2, R3arg, out + 265216);
  k_tfold1<<<4096, 256, 0, stream>>>(ref1, R3arg, out + 789504);
}

// Round 4
// 504.963 us; speedup vs baseline: 1.6692x; 1.1297x over previous
//
#include <hip/hip_runtime.h>

typedef short bf8 __attribute__((ext_vector_type(8)));
typedef float f32x4 __attribute__((ext_vector_type(4)));

static __device__ __forceinline__ unsigned short f2bf(float f) {
  unsigned u = __float_as_uint(f);
  unsigned r = u + 0x7FFFu + ((u >> 16) & 1u);
  return (unsigned short)(r >> 16);
}
static __device__ __forceinline__ float bf2f(unsigned short h) {
  return __uint_as_float(((unsigned)h) << 16);
}
static __device__ __forceinline__ unsigned fkey(float f) {
  unsigned u = __float_as_uint(f);
  return (u & 0x80000000u) ? ~u : (u | 0x80000000u);
}
static __device__ __forceinline__ float kdec(unsigned k) {
  unsigned u = (k & 0x80000000u) ? (k & 0x7FFFFFFFu) : ~k;
  return __uint_as_float(u);
}

// async global->LDS, 16B per lane. lds dest: wave-uniform base + lane*16.
static __device__ __forceinline__ void gload_lds16(const unsigned short* g, unsigned short* l) {
  __builtin_amdgcn_global_load_lds((const __attribute__((address_space(1))) void*)g,
                                   (__attribute__((address_space(3))) void*)l, 16, 0, 0);
}

// unfold(k=3,pad=1,stride=1) value: row d = (cc*3+ki)*3+kj, col m = i*S+j, src [C][S][S]
static __device__ __forceinline__ float uf3(const float* __restrict__ src, int lgS, int d, int m) {
  const int S = 1 << lgS;
  int cc = d / 9;
  int r9 = d - cc * 9;
  int ki = r9 / 3;
  int kj = r9 - ki * 3;
  int i = (m >> lgS) + ki - 1;
  int j = (m & (S - 1)) + kj - 1;
  if ((unsigned)i >= (unsigned)S || (unsigned)j >= (unsigned)S) return 0.f;
  return src[((size_t)cc << (2 * lgS)) + ((size_t)i << lgS) + j];
}

// ---------------- prep kernels ----------------

__global__ __launch_bounds__(256) void k_colnorm(const float* __restrict__ src, float* __restrict__ scale) {
  int m = blockIdx.x;
  float s = 0.f;
  for (int d = threadIdx.x; d < 2304; d += 256) {
    float v = uf3(src, 5, d, m);
    s += v * v;
  }
  __shared__ float red[256];
  red[threadIdx.x] = s; __syncthreads();
  for (int o = 128; o > 0; o >>= 1) { if (threadIdx.x < o) red[threadIdx.x] += red[threadIdx.x + o]; __syncthreads(); }
  if (threadIdx.x == 0) scale[m] = 1.f / fmaxf(sqrtf(red[0]), 1e-12f);
}

// colnorm of lrsr3 + bias dots: scale[m]=1/max(||col||,eps); bl2[m]=(b1.col)*scale; bl1[m]=(b2.col)*scale
__global__ __launch_bounds__(256) void k_colnorm_bl(const float* __restrict__ src,
                                                    const float* __restrict__ b1, const float* __restrict__ b2,
                                                    float* __restrict__ scale,
                                                    float* __restrict__ bl2, float* __restrict__ bl1) {
  int m = blockIdx.x;
  float s = 0.f, d1 = 0.f, d2 = 0.f;
  for (int d = threadIdx.x; d < 2304; d += 256) {
    float v = uf3(src, 5, d, m);
    s += v * v; d1 += b1[d] * v; d2 += b2[d] * v;
  }
  __shared__ float r0[256], r1[256], r2[256];
  r0[threadIdx.x] = s; r1[threadIdx.x] = d1; r2[threadIdx.x] = d2;
  __syncthreads();
  for (int o = 128; o > 0; o >>= 1) {
    if (threadIdx.x < o) {
      r0[threadIdx.x] += r0[threadIdx.x + o];
      r1[threadIdx.x] += r1[threadIdx.x + o];
      r2[threadIdx.x] += r2[threadIdx.x + o];
    }
    __syncthreads();
  }
  if (threadIdx.x == 0) {
    float sc = 1.f / fmaxf(sqrtf(r0[0]), 1e-12f);
    scale[m] = sc; bl2[m] = r1[0] * sc; bl1[m] = r2[0] * sc;
  }
}

// normalized unfold, bf16, layout [m][d]
__global__ __launch_bounds__(256) void k_pass2_md_bf(const float* __restrict__ src, const float* __restrict__ scale, unsigned short* __restrict__ out) {
  int id = blockIdx.x * 256 + threadIdx.x;
  int m = id / 2304, d = id - m * 2304;
  out[id] = f2bf(uf3(src, 5, d, m) * scale[m]);
}
// plain unfold -> bf16, layout [n][c], with column padding (c >= CKreal -> 0)
__global__ __launch_bounds__(256) void k_unfold_bf(const float* __restrict__ src, unsigned short* __restrict__ out,
                                                   int lgS, int CKpad, int CKreal, int total) {
  int id = blockIdx.x * 256 + threadIdx.x;
  if (id >= total) return;
  int n = id / CKpad, c = id - n * CKpad;
  float v = (c < CKreal) ? uf3(src, lgS, c, n) : 0.f;
  out[id] = f2bf(v);
}
// W [2304][Cw] f32 -> Wt [Cw][2304] bf16
__global__ __launch_bounds__(256) void k_wtrans(const float* __restrict__ W, unsigned short* __restrict__ Wt, int Cw, int total) {
  int id = blockIdx.x * 256 + threadIdx.x;
  if (id >= total) return;
  int d = id / Cw, c = id - d * Cw;
  Wt[(size_t)c * 2304 + d] = f2bf(W[id]);
}
// bw[c] += sum_{d in chunk} b[d]*W[d][c]  (bw zero-initialized)
__global__ __launch_bounds__(256) void k_bw(const float* __restrict__ W, const float* __restrict__ b, float* __restrict__ bw,
                                            int CwReal) {
  int c = blockIdx.x * 256 + threadIdx.x;
  if (c >= CwReal) return;
  int d0 = blockIdx.y * 256;
  float s = 0.f;
  for (int d = d0; d < d0 + 256; ++d) s += b[d] * W[(size_t)d * CwReal + c];
  atomicAdd(&bw[c], s);
}
// bb[0]=||b1||^2, bb[1]=||b2||^2
__global__ __launch_bounds__(256) void k_bb(const float* __restrict__ b1, const float* __restrict__ b2, float* __restrict__ bb) {
  const float* b = blockIdx.x ? b2 : b1;
  float s = 0.f;
  for (int d = threadIdx.x; d < 2304; d += 256) s += b[d] * b[d];
  __shared__ float red[256];
  red[threadIdx.x] = s; __syncthreads();
  for (int o = 128; o > 0; o >>= 1) { if (threadIdx.x < o) red[threadIdx.x] += red[threadIdx.x + o]; __syncthreads(); }
  if (threadIdx.x == 0) bb[blockIdx.x] = red[0];
}

// ---------------- bf16 MFMA GEMM: 128x128 tile, BK=64, 4 waves, double-buffered, XOR-swizzled ----------------
// TN form: C[i][j] = sum_k A[i][k]*Bt[j][k].  M,N % 128 == 0, K % 64 == 0.
// EPI 0: store bf16 C[M][N]
// EPI 1: normsq[i] += sum_j C[i][j]*A[i][j], bwdot[i] += sum_j bw[j]*A[i][j]  (N==K; Bt symmetric Gram)
// EPI 2: skey[j] = max_i fkey((C[i][j]+bl[j])*ninv[i])
template <int EPI>
__global__ __launch_bounds__(256) void k_gemm128(const unsigned short* __restrict__ A,
                                                 const unsigned short* __restrict__ Bt,
                                                 unsigned short* __restrict__ C,
                                                 int M, int N, int K,
                                                 const float* __restrict__ bl,
                                                 const float* __restrict__ ninv,
                                                 const float* __restrict__ bw,
                                                 float* __restrict__ normsq,
                                                 float* __restrict__ bwdot,
                                                 unsigned* __restrict__ skey) {
  __shared__ __align__(16) unsigned short As[2][128 * 64];
  __shared__ __align__(16) unsigned short Bs[2][128 * 64];
  __shared__ unsigned colkey[128];
  const int tid = threadIdx.x;
  const int l = tid & 63;
  const int w = tid >> 6;          // wave 0..3
  const int wr = w >> 1, wc = w & 1;
  const int m0 = blockIdx.y * 128, n0 = blockIdx.x * 128;
  if (EPI == 2 && tid < 128) colkey[tid] = 0u;

  f32x4 acc[4][4] = {};

  // staging: wave w stages rows [w*32, w*32+32) in 4 chunks of 8 rows.
  // HW writes lane l at ldsbase + l*16B -> (row chunk+l>>3, slot l&7).
  // Pre-swizzle the GLOBAL source so LDS slot q of row r holds global slot q^(r&7).
  const int srow = w * 32;
  const int lrow = l >> 3;
  const int gcol = ((l & 7) ^ lrow) * 8;   // pre-swizzled global column (elements)
  const int mr = l & 15;                   // fragment col lane
  const int kg = l >> 4;                   // k-octet group

  const int nt = K >> 6;
  const int snap_kb = n0 + wc * 64;        // EPI1: iter whose LDS A-tile holds this wave's epilogue cols
  unsigned short snap[4][4][4];            // [mi][ni][e]

  auto stage = [&](int buf, int kb) {
#pragma unroll
    for (int i = 0; i < 4; ++i) {
      int r = srow + i * 8;
      gload_lds16(A  + (size_t)(m0 + r + lrow) * K + kb + gcol, &As[buf][r * 64]);
      gload_lds16(Bt + (size_t)(n0 + r + lrow) * K + kb + gcol, &Bs[buf][r * 64]);
    }
  };

  stage(0, 0);
  __syncthreads();                 // vmcnt(0) drain + barrier: tile 0 ready
  int cur = 0;
  for (int t = 0; t < nt; ++t) {
    const int kb = t << 6;
    if (t + 1 < nt) stage(cur ^ 1, kb + 64);   // prefetch next tile; drains at END of this iter
#pragma unroll
    for (int ks = 0; ks < 2; ++ks) {
      bf8 af[4], bv[4];
#pragma unroll
      for (int mi = 0; mi < 4; ++mi) {
        const int row = wr * 64 + mi * 16 + mr;
        af[mi] = *(const bf8*)&As[cur][row * 64 + (((ks * 4 + kg) ^ (row & 7)) * 8)];
      }
#pragma unroll
      for (int ni = 0; ni < 4; ++ni) {
        const int row = wc * 64 + ni * 16 + mr;
        bv[ni] = *(const bf8*)&Bs[cur][row * 64 + (((ks * 4 + kg) ^ (row & 7)) * 8)];
      }
#pragma unroll
      for (int mi = 0; mi < 4; ++mi)
#pragma unroll
        for (int ni = 0; ni < 4; ++ni)
          acc[mi][ni] = __builtin_amdgcn_mfma_f32_16x16x32_bf16(af[mi], bv[ni], acc[mi][ni], 0, 0, 0);
    }
    if (EPI == 1 && kb == snap_kb) {
      // snapshot the A values this lane's accumulator rows/cols need (for quadratic form + bw dot)
#pragma unroll
      for (int mi = 0; mi < 4; ++mi)
#pragma unroll
        for (int e = 0; e < 4; ++e) {
          const int row = wr * 64 + mi * 16 + kg * 4 + e;
#pragma unroll
          for (int ni = 0; ni < 4; ++ni) {
            const int slot = ni * 2 + (mr >> 3);
            snap[mi][ni][e] = As[cur][row * 64 + ((slot ^ (row & 7)) * 8) + (mr & 7)];
          }
        }
    }
    __syncthreads();               // drains this iter's prefetch (vmcnt) + all LDS reads (lgkm)
    cur ^= 1;
  }

  // C/D frag layout: col = mr, row = kg*4 + e (within 16x16)
  const int gr0 = m0 + wr * 64;    // + mi*16 + kg*4 + e
  const int gc0 = n0 + wc * 64;    // + ni*16 + mr
  if (EPI == 0) {
#pragma unroll
    for (int mi = 0; mi < 4; ++mi)
#pragma unroll
      for (int ni = 0; ni < 4; ++ni)
#pragma unroll
        for (int e = 0; e < 4; ++e)
          C[(size_t)(gr0 + mi * 16 + kg * 4 + e) * (size_t)N + (gc0 + ni * 16 + mr)] = f2bf(acc[mi][ni][e]);
  } else if (EPI == 1) {
    float rp[4][4] = {};
    float bp[4][4] = {};
#pragma unroll
    for (int ni = 0; ni < 4; ++ni) {
      const float bwv = bw[gc0 + ni * 16 + mr];
#pragma unroll
      for (int mi = 0; mi < 4; ++mi)
#pragma unroll
        for (int e = 0; e < 4; ++e) {
          const float av = bf2f(snap[mi][ni][e]);
          rp[mi][e] += acc[mi][ni][e] * av;
          bp[mi][e] += bwv * av;
        }
    }
#pragma unroll
    for (int off = 1; off < 16; off <<= 1)
#pragma unroll
      for (int mi = 0; mi < 4; ++mi)
#pragma unroll
        for (int e = 0; e < 4; ++e) {
          rp[mi][e] += __shfl_xor(rp[mi][e], off);
          bp[mi][e] += __shfl_xor(bp[mi][e], off);
        }
    if (mr == 0) {
#pragma unroll
      for (int mi = 0; mi < 4; ++mi)
#pragma unroll
        for (int e = 0; e < 4; ++e) {
          atomicAdd(&normsq[gr0 + mi * 16 + kg * 4 + e], rp[mi][e]);
          atomicAdd(&bwdot[gr0 + mi * 16 + kg * 4 + e], bp[mi][e]);
        }
    }
  } else {
    float nv[4][4];
#pragma unroll
    for (int mi = 0; mi < 4; ++mi)
#pragma unroll
      for (int e = 0; e < 4; ++e) nv[mi][e] = ninv[gr0 + mi * 16 + kg * 4 + e];
#pragma unroll
    for (int ni = 0; ni < 4; ++ni) {
      float blv = bl[gc0 + ni * 16 + mr];
      float mx = -3.0e38f;
#pragma unroll
      for (int mi = 0; mi < 4; ++mi)
#pragma unroll
        for (int e = 0; e < 4; ++e) mx = fmaxf(mx, (acc[mi][ni][e] + blv) * nv[mi][e]);
      atomicMax(&colkey[wc * 64 + ni * 16 + mr], fkey(mx));
    }
    __syncthreads();
    if (tid < 128) atomicMax(&skey[n0 + tid], colkey[tid]);
  }
}

// ninv[n] = 1/max(sqrt(max(normsq[n] + 2*bwdot[n] + bb[which],0)),eps)
__global__ __launch_bounds__(256) void k_ninv(const float* __restrict__ normsq, const float* __restrict__ bwdot,
                                              const float* __restrict__ bb, int which,
                                              float* __restrict__ ninv, int n) {
  int i = blockIdx.x * 256 + threadIdx.x;
  if (i >= n) return;
  float t = normsq[i] + 2.f * bwdot[i] + bb[which];
  ninv[i] = 1.f / fmaxf(sqrtf(fmaxf(t, 0.f)), 1e-12f);
}

// ---------------- fp32 pixel Gram: G2[m][n] = sum_c L[c][m]*R[c][n], 1024x1024, K=256 ----------------
__global__ __launch_bounds__(256) void k_pixgram(const float* __restrict__ L, const float* __restrict__ R,
                                                 float* __restrict__ G2) {
  __shared__ float As[16][32];  // [k][m]
  __shared__ float Bs[16][32];  // [k][n]
  const int tid = threadIdx.x;
  const int tx = tid & 15, ty = tid >> 4;
  const int m0 = blockIdx.y * 32, n0 = blockIdx.x * 32;
  float acc[2][2] = {};
  for (int kb = 0; kb < 256; kb += 16) {
    __syncthreads();
    {
      int kk = tid >> 5, mm = tid & 31;
      As[kk][mm] = L[(size_t)(kb + kk) * 1024 + m0 + mm];
      Bs[kk][mm] = R[(size_t)(kb + kk) * 1024 + n0 + mm];
      int e2 = tid + 256; int kk2 = e2 >> 5, mm2 = e2 & 31;
      As[kk2][mm2] = L[(size_t)(kb + kk2) * 1024 + m0 + mm2];
      Bs[kk2][mm2] = R[(size_t)(kb + kk2) * 1024 + n0 + mm2];
    }
    __syncthreads();
#pragma unroll
    for (int kk = 0; kk < 16; ++kk) {
      float a0 = As[kk][ty * 2], a1 = As[kk][ty * 2 + 1];
      float b0 = Bs[kk][tx * 2], b1 = Bs[kk][tx * 2 + 1];
      acc[0][0] = fmaf(a0, b0, acc[0][0]); acc[0][1] = fmaf(a0, b1, acc[0][1]);
      acc[1][0] = fmaf(a1, b0, acc[1][0]); acc[1][1] = fmaf(a1, b1, acc[1][1]);
    }
  }
#pragma unroll
  for (int i = 0; i < 2; ++i)
#pragma unroll
    for (int j = 0; j < 2; ++j)
      G2[(size_t)(m0 + ty * 2 + i) * 1024 + (n0 + tx * 2 + j)] = acc[i][j];
}

// ---------------- R3 max/argmax from pixel Gram via masked 9-point diagonal-shift sum ----------------
__global__ __launch_bounds__(256) void k_r3max(const float* __restrict__ G2, const float* __restrict__ scu3,
                                               const float* __restrict__ sclr,
                                               float* __restrict__ s3, int* __restrict__ arg) {
  const int m = blockIdx.x;
  const int mi = m >> 5, mj = m & 31;
  float best = -3.0e38f; int bi = 0;
  for (int n = threadIdx.x; n < 1024; n += 256) {
    const int ni = n >> 5, nj = n & 31;
    float raw = 0.f;
#pragma unroll
    for (int dy = -1; dy <= 1; ++dy) {
#pragma unroll
      for (int dx = -1; dx <= 1; ++dx) {
        bool vm = ((unsigned)(mi + dy) < 32u) && ((unsigned)(mj + dx) < 32u);
        bool vn = ((unsigned)(ni + dy) < 32u) && ((unsigned)(nj + dx) < 32u);
        if (vm && vn) {
          int off = dy * 32 + dx;
          raw += G2[(size_t)(m + off) * 1024 + (n + off)];
        }
      }
    }
    float v = raw * scu3[n];
    if (v > best) { best = v; bi = n; }
  }
  __shared__ float bv[256]; __shared__ int bidx[256];
  bv[threadIdx.x] = best; bidx[threadIdx.x] = bi;
  __syncthreads();
  for (int o = 128; o > 0; o >>= 1) {
    if (threadIdx.x < o) {
      float ov = bv[threadIdx.x + o]; int oi = bidx[threadIdx.x + o];
      if (ov > bv[threadIdx.x] || (ov == bv[threadIdx.x] && oi < bidx[threadIdx.x])) {
        bv[threadIdx.x] = ov; bidx[threadIdx.x] = oi;
      }
    }
    __syncthreads();
  }
  if (threadIdx.x == 0) { s3[m] = bv[0] * sclr[m]; arg[m] = bidx[0]; }
}

__global__ __launch_bounds__(256) void k_finS(const unsigned* __restrict__ k1, const unsigned* __restrict__ k2, float* __restrict__ out) {
  int t = blockIdx.x * 256 + threadIdx.x;
  if (t < 1024) { out[t] = kdec(k1[t]); out[1024 + t] = kdec(k2[t]); }
}

// ---------------- gather + fold ----------------
__global__ __launch_bounds__(256) void k_tfold3(const float* __restrict__ ref, const int* __restrict__ arg, float* __restrict__ out) {
  int id = blockIdx.x * 256 + threadIdx.x;
  int c = id >> 10, rem = id & 1023;
  int y = rem >> 5, x = rem & 31;
  float s = 0.f;
#pragma unroll
  for (int ki = 0; ki < 3; ++ki) {
    int i = y + 1 - ki;
    if ((unsigned)i >= 32u) continue;
#pragma unroll
    for (int kj = 0; kj < 3; ++kj) {
      int j = x + 1 - kj;
      if ((unsigned)j >= 32u) continue;
      int n2 = arg[i * 32 + j];
      int rr = (n2 >> 5) + ki - 1, cc = (n2 & 31) + kj - 1;
      if ((unsigned)rr < 32u && (unsigned)cc < 32u) s += ref[(size_t)c * 1024 + rr * 32 + cc];
    }
  }
  out[id] = s * (1.f / 9.f);
}
__global__ __launch_bounds__(256) void k_tfold2(const float* __restrict__ ref, const int* __restrict__ arg, float* __restrict__ out) {
  int id = blockIdx.x * 256 + threadIdx.x;
  int c = id >> 12, rem = id & 4095;
  int y = rem >> 6, x = rem & 63;
  float s = 0.f;
#pragma unroll
  for (int ki = 0; ki < 6; ++ki) {
    int t = y + 2 - ki;
    if (t < 0 || (t & 1)) continue;
    int i = t >> 1;
    if (i >= 32) continue;
#pragma unroll
    for (int kj = 0; kj < 6; ++kj) {
      int t2 = x + 2 - kj;
      if (t2 < 0 || (t2 & 1)) continue;
      int j = t2 >> 1;
      if (j >= 32) continue;
      int n2 = arg[i * 32 + j];
      int rr = (n2 >> 5) * 2 + ki - 2, cc = (n2 & 31) * 2 + kj - 2;
      if ((unsigned)rr < 64u && (unsigned)cc < 64u) s += ref[(size_t)c * 4096 + rr * 64 + cc];
    }
  }
  out[id] = s * (1.f / 9.f);
}
__global__ __launch_bounds__(256) void k_tfold1(const float* __restrict__ ref, const int* __restrict__ arg, float* __restrict__ out) {
  int id = blockIdx.x * 256 + threadIdx.x;
  int c = id >> 14, rem = id & 16383;
  int y = rem >> 7, x = rem & 127;
  float s = 0.f;
#pragma unroll
  for (int ki = 0; ki < 12; ++ki) {
    int t = y + 4 - ki;
    if (t < 0 || (t & 3)) continue;
    int i = t >> 2;
    if (i >= 32) continue;
#pragma unroll
    for (int kj = 0; kj < 12; ++kj) {
      int t2 = x + 4 - kj;
      if (t2 < 0 || (t2 & 3)) continue;
      int j = t2 >> 2;
      if (j >= 32) continue;
      int n2 = arg[i * 32 + j];
      int rr = (n2 >> 5) * 4 + ki - 4, cc = (n2 & 31) * 4 + kj - 4;
      if ((unsigned)rr < 128u && (unsigned)cc < 128u) s += ref[(size_t)c * 16384 + rr * 128 + cc];
    }
  }
  out[id] = s * (1.f / 9.f);
}

// ---------------- workspace layout (bytes) ----------------
// zero-initialized region (memset each launch):
static constexpr size_t OFF_NORMSQ2 = 0;              // 4096 f32
static constexpr size_t OFF_NORMSQ1 = 16384;          // 16384 f32
static constexpr size_t OFF_BWD2    = 81920;          // 4096 f32
static constexpr size_t OFF_BWD1    = 98304;          // 16384 f32
static constexpr size_t OFF_S1KEY   = 163840;         // 1024 u32
static constexpr size_t OFF_S2KEY   = 167936;         // 1024 u32
static constexpr size_t OFF_BW2     = 172032;         // 1152 f32
static constexpr size_t OFF_BW1     = 176640;         // 640 f32
static constexpr size_t ZERO_BYTES  = 179200;
// non-zeroed:
static constexpr size_t OFF_BL2     = 179200;                   // f32 [1024]
static constexpr size_t OFF_BL1     = 183296;                   // f32 [1024]
static constexpr size_t OFF_LR3NBT  = 187392;                   // bf16 [1024][2304]
static constexpr size_t OFF_U2B     = OFF_LR3NBT + 4718592;     // bf16 [4096][1152]
static constexpr size_t OFF_U1B     = OFF_U2B    + 9437184;     // bf16 [16384][640] (cols 576+ zero)
static constexpr size_t OFF_W1T     = OFF_U1B    + 20971520;    // bf16 [1152][2304]
static constexpr size_t OFF_W2T     = OFF_W1T    + 5308416;     // bf16 [640][2304] (rows 576+ zero)
static constexpr size_t OFF_A2      = OFF_W2T    + 2949120;     // bf16 [1152][1152]
static constexpr size_t OFF_A1      = OFF_A2     + 2654208;     // bf16 [640][640]
static constexpr size_t OFF_M2T     = OFF_A1     + 819200;      // bf16 [1024][1152]
static constexpr size_t OFF_M1T     = OFF_M2T    + 2359296;     // bf16 [1024][640]
static constexpr size_t OFF_G2      = OFF_M1T    + 1310720;     // f32 [1024][1024]
static constexpr size_t OFF_R3ARG   = OFF_G2     + 4194304;     // int [1024]
static constexpr size_t OFF_SCLR    = OFF_R3ARG  + 4096;        // f32 [1024]
static constexpr size_t OFF_SCU3    = OFF_SCLR   + 4096;        // f32 [1024]
static constexpr size_t OFF_BB      = OFF_SCU3   + 4096;        // f32 [2]
static constexpr size_t OFF_N2INV   = OFF_BB     + 256;         // f32 [4096]
static constexpr size_t OFF_N1INV   = OFF_N2INV  + 16384;       // f32 [16384]

extern "C" void kernel_launch(void* const* d_in, const int* in_sizes, int n_in,
                              void* d_out, int out_size, void* d_ws, size_t ws_size,
                              hipStream_t stream) {
  (void)in_sizes; (void)n_in; (void)out_size; (void)ws_size;
  const float* lrsr3  = (const float*)d_in[0];
  const float* rsr1   = (const float*)d_in[1];
  const float* rsr2   = (const float*)d_in[2];
  const float* rsr3   = (const float*)d_in[3];
  const float* ref1   = (const float*)d_in[4];
  const float* ref2   = (const float*)d_in[5];
  const float* ref3   = (const float*)d_in[6];
  const float* W1     = (const float*)d_in[7];
  const float* b1     = (const float*)d_in[8];
  const float* W2     = (const float*)d_in[9];
  const float* b2     = (const float*)d_in[10];
  float* out = (float*)d_out;
  char* ws = (char*)d_ws;

  float*          normsq2 = (float*)(ws + OFF_NORMSQ2);
  float*          normsq1 = (float*)(ws + OFF_NORMSQ1);
  float*          bwd2    = (float*)(ws + OFF_BWD2);
  float*          bwd1    = (float*)(ws + OFF_BWD1);
  unsigned*       s1key   = (unsigned*)(ws + OFF_S1KEY);
  unsigned*       s2key   = (unsigned*)(ws + OFF_S2KEY);
  float*          bw2     = (float*)(ws + OFF_BW2);
  float*          bw1     = (float*)(ws + OFF_BW1);
  float*          bl2     = (float*)(ws + OFF_BL2);
  float*          bl1     = (float*)(ws + OFF_BL1);
  unsigned short* lr3nbT  = (unsigned short*)(ws + OFF_LR3NBT);
  unsigned short* U2b     = (unsigned short*)(ws + OFF_U2B);
  unsigned short* U1b     = (unsigned short*)(ws + OFF_U1B);
  unsigned short* W1t     = (unsigned short*)(ws + OFF_W1T);
  unsigned short* W2t     = (unsigned short*)(ws + OFF_W2T);
  unsigned short* A2b     = (unsigned short*)(ws + OFF_A2);
  unsigned short* A1b     = (unsigned short*)(ws + OFF_A1);
  unsigned short* M2tb    = (unsigned short*)(ws + OFF_M2T);
  unsigned short* M1tb    = (unsigned short*)(ws + OFF_M1T);
  float*          G2      = (float*)(ws + OFF_G2);
  int*            R3arg   = (int*)(ws + OFF_R3ARG);
  float*          sclr    = (float*)(ws + OFF_SCLR);
  float*          scu3    = (float*)(ws + OFF_SCU3);
  float*          bb      = (float*)(ws + OFF_BB);
  float*          n2inv   = (float*)(ws + OFF_N2INV);
  float*          n1inv   = (float*)(ws + OFF_N1INV);

  hipMemsetAsync(d_ws, 0, ZERO_BYTES, stream);
  // zero pad rows 576..639 of W2t
  hipMemsetAsync(ws + OFF_W2T + (size_t)576 * 2304 * 2, 0, (size_t)64 * 2304 * 2, stream);

  // norms + bias dots + pixel Gram (R3 path, all fp32, no unfold materialization)
  k_colnorm_bl<<<1024, 256, 0, stream>>>(lrsr3, b1, b2, sclr, bl2, bl1);
  k_colnorm<<<1024, 256, 0, stream>>>(rsr3, scu3);
  k_pixgram<<<dim3(32, 32), 256, 0, stream>>>(lrsr3, rsr3, G2);
  k_r3max<<<1024, 256, 0, stream>>>(G2, scu3, sclr, out + 2048, R3arg);

  // unfolds / transposes for the bf16 score paths
  k_pass2_md_bf<<<9216, 256, 0, stream>>>(lrsr3, sclr, lr3nbT);
  k_unfold_bf<<<18432, 256, 0, stream>>>(rsr2, U2b, 6, 1152, 1152, 4096 * 1152);
  k_unfold_bf<<<40960, 256, 0, stream>>>(rsr1, U1b, 7, 640, 576, 16384 * 640);
  k_wtrans<<<10368, 256, 0, stream>>>(W1, W1t, 1152, 2304 * 1152);
  k_wtrans<<<5184, 256, 0, stream>>>(W2, W2t, 576, 2304 * 576);
  k_bw<<<dim3(5, 9), 256, 0, stream>>>(W1, b1, bw2, 1152);
  k_bw<<<dim3(3, 9), 256, 0, stream>>>(W2, b2, bw1, 576);
  k_bb<<<2, 256, 0, stream>>>(b1, b2, bb);

  // Gram matrices A = Wt @ Wt^T (symmetric) and M^T = lr3n^T @ W^T
  k_gemm128<0><<<dim3(9, 9), 256, 0, stream>>>(W1t, W1t, A2b, 1152, 1152, 2304, nullptr, nullptr, nullptr, nullptr, nullptr, nullptr);
  k_gemm128<0><<<dim3(5, 5), 256, 0, stream>>>(W2t, W2t, A1b, 640, 640, 2304, nullptr, nullptr, nullptr, nullptr, nullptr, nullptr);
  k_gemm128<0><<<dim3(9, 8), 256, 0, stream>>>(lr3nbT, W1t, M2tb, 1024, 1152, 2304, nullptr, nullptr, nullptr, nullptr, nullptr, nullptr);
  k_gemm128<0><<<dim3(5, 8), 256, 0, stream>>>(lr3nbT, W2t, M1tb, 1024, 640, 2304, nullptr, nullptr, nullptr, nullptr, nullptr, nullptr);
  // norms + bw dots via Gram quadratic form (epilogue uses LDS snapshot, no global re-read)
  k_gemm128<1><<<dim3(9, 32), 256, 0, stream>>>(U2b, A2b, nullptr, 4096, 1152, 1152, nullptr, nullptr, bw2, normsq2, bwd2, nullptr);
  k_gemm128<1><<<dim3(5, 128), 256, 0, stream>>>(U1b, A1b, nullptr, 16384, 640, 640, nullptr, nullptr, bw1, normsq1, bwd1, nullptr);
  k_ninv<<<16, 256, 0, stream>>>(normsq2, bwd2, bb, 0, n2inv, 4096);
  k_ninv<<<64, 256, 0, stream>>>(normsq1, bwd1, bb, 1, n1inv, 16384);
  // score max: S = max_n (U@M^T + bl)/norm
  k_gemm128<2><<<dim3(8, 32), 256, 0, stream>>>(U2b, M2tb, nullptr, 4096, 1024, 1152, bl2, n2inv, nullptr, nullptr, nullptr, s2key);
  k_gemm128<2><<<dim3(8, 128), 256, 0, stream>>>(U1b, M1tb, nullptr, 16384, 1024, 640, bl1, n1inv, nullptr, nullptr, nullptr, s1key);

  k_finS<<<4, 256, 0, stream>>>(s1key, s2key, out);

  // transfer: gather chosen columns and fold
  k_tfold3<<<1024, 256, 0, stream>>>(ref3, R3arg, out + 3072);
  k_tfold2<<<2048, 256, 0, stream>>>(ref2, R3arg, out + 265216);
  k_tfold1<<<4096, 256, 0, stream>>>(ref1, R3arg, out + 789504);
}

// Round 5
// 357.456 us; speedup vs baseline: 2.3580x; 1.4127x over previous
//
#include <hip/hip_runtime.h>

typedef short bf8 __attribute__((ext_vector_type(8)));
typedef float f32x4 __attribute__((ext_vector_type(4)));

static __device__ __forceinline__ unsigned short f2bf(float f) {
  unsigned u = __float_as_uint(f);
  unsigned r = u + 0x7FFFu + ((u >> 16) & 1u);
  return (unsigned short)(r >> 16);
}
static __device__ __forceinline__ float bf2f(unsigned short h) {
  return __uint_as_float(((unsigned)h) << 16);
}
static __device__ __forceinline__ unsigned fkey(float f) {
  unsigned u = __float_as_uint(f);
  return (u & 0x80000000u) ? ~u : (u | 0x80000000u);
}
static __device__ __forceinline__ float kdec(unsigned k) {
  unsigned u = (k & 0x80000000u) ? (k & 0x7FFFFFFFu) : ~k;
  return __uint_as_float(u);
}

// async global->LDS, 16B per lane. lds dest: wave-uniform base + lane*16.
static __device__ __forceinline__ void gload_lds16(const unsigned short* g, unsigned short* l) {
  __builtin_amdgcn_global_load_lds((const __attribute__((address_space(1))) void*)g,
                                   (__attribute__((address_space(3))) void*)l, 16, 0, 0);
}

// unfold(k=3,pad=1,stride=1) value: row d = (cc*3+ki)*3+kj, col m = i*S+j, src [C][S][S]
static __device__ __forceinline__ float uf3(const float* __restrict__ src, int lgS, int d, int m) {
  const int S = 1 << lgS;
  int cc = d / 9;
  int r9 = d - cc * 9;
  int ki = r9 / 3;
  int kj = r9 - ki * 3;
  int i = (m >> lgS) + ki - 1;
  int j = (m & (S - 1)) + kj - 1;
  if ((unsigned)i >= (unsigned)S || (unsigned)j >= (unsigned)S) return 0.f;
  return src[((size_t)cc << (2 * lgS)) + ((size_t)i << lgS) + j];
}

// ---------------- prep kernels ----------------

__global__ __launch_bounds__(256) void k_colnorm(const float* __restrict__ src, float* __restrict__ scale) {
  int m = blockIdx.x;
  float s = 0.f;
  for (int d = threadIdx.x; d < 2304; d += 256) {
    float v = uf3(src, 5, d, m);
    s += v * v;
  }
  __shared__ float red[256];
  red[threadIdx.x] = s; __syncthreads();
  for (int o = 128; o > 0; o >>= 1) { if (threadIdx.x < o) red[threadIdx.x] += red[threadIdx.x + o]; __syncthreads(); }
  if (threadIdx.x == 0) scale[m] = 1.f / fmaxf(sqrtf(red[0]), 1e-12f);
}

// colnorm of lrsr3 + bias dots: scale[m]=1/max(||col||,eps); bl2[m]=(b1.col)*scale; bl1[m]=(b2.col)*scale
__global__ __launch_bounds__(256) void k_colnorm_bl(const float* __restrict__ src,
                                                    const float* __restrict__ b1, const float* __restrict__ b2,
                                                    float* __restrict__ scale,
                                                    float* __restrict__ bl2, float* __restrict__ bl1) {
  int m = blockIdx.x;
  float s = 0.f, d1 = 0.f, d2 = 0.f;
  for (int d = threadIdx.x; d < 2304; d += 256) {
    float v = uf3(src, 5, d, m);
    s += v * v; d1 += b1[d] * v; d2 += b2[d] * v;
  }
  __shared__ float r0[256], r1[256], r2[256];
  r0[threadIdx.x] = s; r1[threadIdx.x] = d1; r2[threadIdx.x] = d2;
  __syncthreads();
  for (int o = 128; o > 0; o >>= 1) {
    if (threadIdx.x < o) {
      r0[threadIdx.x] += r0[threadIdx.x + o];
      r1[threadIdx.x] += r1[threadIdx.x + o];
      r2[threadIdx.x] += r2[threadIdx.x + o];
    }
    __syncthreads();
  }
  if (threadIdx.x == 0) {
    float sc = 1.f / fmaxf(sqrtf(r0[0]), 1e-12f);
    scale[m] = sc; bl2[m] = r1[0] * sc; bl1[m] = r2[0] * sc;
  }
}

// normalized unfold, bf16, layout [m][d]
__global__ __launch_bounds__(256) void k_pass2_md_bf(const float* __restrict__ src, const float* __restrict__ scale, unsigned short* __restrict__ out) {
  int id = blockIdx.x * 256 + threadIdx.x;
  int m = id / 2304, d = id - m * 2304;
  out[id] = f2bf(uf3(src, 5, d, m) * scale[m]);
}
// plain unfold -> bf16, layout [n][c], with column padding (c >= CKreal -> 0)
__global__ __launch_bounds__(256) void k_unfold_bf(const float* __restrict__ src, unsigned short* __restrict__ out,
                                                   int lgS, int CKpad, int CKreal, int total) {
  int id = blockIdx.x * 256 + threadIdx.x;
  if (id >= total) return;
  int n = id / CKpad, c = id - n * CKpad;
  float v = (c < CKreal) ? uf3(src, lgS, c, n) : 0.f;
  out[id] = f2bf(v);
}
// W [2304][Cw] f32 -> Wt [Cw][2304] bf16, LDS-tiled 64x64 (coalesced both sides)
__global__ __launch_bounds__(256) void k_wtransT(const float* __restrict__ W, unsigned short* __restrict__ Wt, int Cw) {
  __shared__ unsigned short Ls[64][65];
  const int c0 = blockIdx.x * 64;   // input col block = output row block
  const int d0 = blockIdx.y * 64;   // input row block
#pragma unroll
  for (int i = 0; i < 16; ++i) {
    int idx = threadIdx.x + i * 256;
    int r = idx >> 6, c = idx & 63;
    Ls[r][c] = f2bf(W[(size_t)(d0 + r) * Cw + c0 + c]);
  }
  __syncthreads();
#pragma unroll
  for (int i = 0; i < 16; ++i) {
    int idx = threadIdx.x + i * 256;
    int cc = idx >> 6, rr = idx & 63;
    Wt[(size_t)(c0 + cc) * 2304 + d0 + rr] = Ls[rr][cc];
  }
}
// bw[c] += sum_{d in chunk} b[d]*W[d][c]  (bw zero-initialized)
__global__ __launch_bounds__(256) void k_bw(const float* __restrict__ W, const float* __restrict__ b, float* __restrict__ bw,
                                            int CwReal) {
  int c = blockIdx.x * 256 + threadIdx.x;
  if (c >= CwReal) return;
  int d0 = blockIdx.y * 256;
  float s = 0.f;
  for (int d = d0; d < d0 + 256; ++d) s += b[d] * W[(size_t)d * CwReal + c];
  atomicAdd(&bw[c], s);
}
// bb[0]=||b1||^2, bb[1]=||b2||^2
__global__ __launch_bounds__(256) void k_bb(const float* __restrict__ b1, const float* __restrict__ b2, float* __restrict__ bb) {
  const float* b = blockIdx.x ? b2 : b1;
  float s = 0.f;
  for (int d = threadIdx.x; d < 2304; d += 256) s += b[d] * b[d];
  __shared__ float red[256];
  red[threadIdx.x] = s; __syncthreads();
  for (int o = 128; o > 0; o >>= 1) { if (threadIdx.x < o) red[threadIdx.x] += red[threadIdx.x + o]; __syncthreads(); }
  if (threadIdx.x == 0) bb[blockIdx.x] = red[0];
}

// ---------------- bf16 MFMA GEMM: 128x128 tile, BK=64, 4 waves, counted-vmcnt pipeline ----------------
// TN form: C[i][j] = sum_k A[i][k]*Bt[j][k].  Rows split across two source/dest buffers at Msplit.
// Two jobs per dispatch (block id < nb0 -> j0). K % 64 == 0, K >= 128.
// EPI 0: store bf16 C
// EPI 1: nsq_out[i] += sum_j C[i][j]*A[i][j]; bwd_out[i] += sum_j bw[j]*A[i][j]  (N==K; Bt symmetric Gram)
// EPI 2: skey[j] = max_i fkey((C[i][j]+bl[j]) / max(sqrt(max(normsq[i]+2*bwdot[i]+bb[which],0)),eps))
struct Job {
  const unsigned short* Alo;
  const unsigned short* Ahi;
  const unsigned short* Bt;
  unsigned short* Clo;
  unsigned short* Chi;
  const float* bl;
  const float* normsq;
  const float* bwdot;
  const float* bb;
  const float* bw;
  float* nsq_out;
  float* bwd_out;
  unsigned* skey;
  int Msplit, N, K, nbx, which;
};

template <int EPI>
__global__ __launch_bounds__(256) void k_gemm128(Job j0, Job j1, int nb0) {
  __shared__ __align__(16) unsigned short As[2][128 * 64];
  __shared__ __align__(16) unsigned short Bs[2][128 * 64];
  __shared__ unsigned colkey[128];
  const bool first = ((int)blockIdx.x < nb0);
  const Job j = first ? j0 : j1;
  const int local = (int)blockIdx.x - (first ? 0 : nb0);
  const int by = local / j.nbx;
  const int bx = local - by * j.nbx;
  const int m0 = by * 128, n0 = bx * 128;
  const int K = j.K, N = j.N;

  const unsigned short* Abase = (m0 < j.Msplit)
      ? j.Alo + (size_t)m0 * K
      : j.Ahi + (size_t)(m0 - j.Msplit) * K;

  const int tid = threadIdx.x;
  const int l = tid & 63;
  const int w = tid >> 6;          // wave 0..3
  const int wr = w >> 1, wc = w & 1;
  if (EPI == 2 && tid < 128) colkey[tid] = 0u;

  f32x4 acc[4][4] = {};

  // staging: wave w stages rows [w*32, w*32+32) in 4 chunks of 8 rows.
  // HW writes lane l at ldsbase + l*16B -> (row chunk+l>>3, slot l&7).
  // Pre-swizzle GLOBAL source so LDS slot q of row r holds global slot q^(r&7).
  const int srow = w * 32;
  const int lrow = l >> 3;
  const int gcol = ((l & 7) ^ lrow) * 8;
  const int mr = l & 15;
  const int kg = l >> 4;

  const int nt = K >> 6;
  const int snap_kb = n0 + wc * 64;
  unsigned short snap[4][4][4];

  auto stage = [&](int buf, int kb) {
#pragma unroll
    for (int i = 0; i < 4; ++i) {
      int r = srow + i * 8;
      gload_lds16(Abase + (size_t)(r + lrow) * K + kb + gcol, &As[buf][r * 64]);
      gload_lds16(j.Bt + (size_t)(n0 + r + lrow) * K + kb + gcol, &Bs[buf][r * 64]);
    }
  };

  // prologue: tiles 0 and 1 in flight; wait tile 0 (8 newest stay outstanding)
  stage(0, 0);
  stage(1, 64);
  asm volatile("s_waitcnt vmcnt(8)\ns_barrier" ::: "memory");

  int cur = 0;
  for (int t = 0; t < nt; ++t) {
#pragma unroll
    for (int ks = 0; ks < 2; ++ks) {
      bf8 af[4], bv[4];
#pragma unroll
      for (int mi = 0; mi < 4; ++mi) {
        const int row = wr * 64 + mi * 16 + mr;
        af[mi] = *(const bf8*)&As[cur][row * 64 + (((ks * 4 + kg) ^ (row & 7)) * 8)];
      }
#pragma unroll
      for (int ni = 0; ni < 4; ++ni) {
        const int row = wc * 64 + ni * 16 + mr;
        bv[ni] = *(const bf8*)&Bs[cur][row * 64 + (((ks * 4 + kg) ^ (row & 7)) * 8)];
      }
#pragma unroll
      for (int mi = 0; mi < 4; ++mi)
#pragma unroll
        for (int ni = 0; ni < 4; ++ni)
          acc[mi][ni] = __builtin_amdgcn_mfma_f32_16x16x32_bf16(af[mi], bv[ni], acc[mi][ni], 0, 0, 0);
    }
    if (EPI == 1 && (t << 6) == snap_kb) {
      // snapshot A values this lane's accumulator rows/cols need (quadratic form + bw dot)
#pragma unroll
      for (int mi = 0; mi < 4; ++mi)
#pragma unroll
        for (int e = 0; e < 4; ++e) {
          const int row = wr * 64 + mi * 16 + kg * 4 + e;
#pragma unroll
          for (int ni = 0; ni < 4; ++ni) {
            const int slot = ni * 2 + (mr >> 3);
            snap[mi][ni][e] = As[cur][row * 64 + ((slot ^ (row & 7)) * 8) + (mr & 7)];
          }
        }
    }
    if (t + 1 < nt) {
      asm volatile("s_waitcnt lgkmcnt(0)\ns_barrier" ::: "memory");   // buf[cur] free everywhere
      if (t + 2 < nt) {
        stage(cur, (t + 2) << 6);                                     // refill freed buffer
        asm volatile("s_waitcnt vmcnt(8)\ns_barrier" ::: "memory");   // tile t+1 landed; t+2 in flight
      } else {
        asm volatile("s_waitcnt vmcnt(0)\ns_barrier" ::: "memory");   // drain last prefetch
      }
      cur ^= 1;
    }
  }

  // C/D frag layout: col = mr, row = kg*4 + e (within 16x16)
  const int lr0 = wr * 64;         // + mi*16 + kg*4 + e (tile-relative row)
  const int lc0 = wc * 64;         // + ni*16 + mr       (tile-relative col)
  if (EPI == 0) {
    unsigned short* Cbase = (m0 < j.Msplit)
        ? j.Clo + (size_t)m0 * N
        : j.Chi + (size_t)(m0 - j.Msplit) * N;
#pragma unroll
    for (int mi = 0; mi < 4; ++mi)
#pragma unroll
      for (int ni = 0; ni < 4; ++ni)
#pragma unroll
        for (int e = 0; e < 4; ++e)
          Cbase[(size_t)(lr0 + mi * 16 + kg * 4 + e) * (size_t)N + (n0 + lc0 + ni * 16 + mr)] = f2bf(acc[mi][ni][e]);
  } else if (EPI == 1) {
    float rp[4][4] = {};
    float bp[4][4] = {};
#pragma unroll
    for (int ni = 0; ni < 4; ++ni) {
      const float bwv = j.bw[n0 + lc0 + ni * 16 + mr];
#pragma unroll
      for (int mi = 0; mi < 4; ++mi)
#pragma unroll
        for (int e = 0; e < 4; ++e) {
          const float av = bf2f(snap[mi][ni][e]);
          rp[mi][e] += acc[mi][ni][e] * av;
          bp[mi][e] += bwv * av;
        }
    }
#pragma unroll
    for (int off = 1; off < 16; off <<= 1)
#pragma unroll
      for (int mi = 0; mi < 4; ++mi)
#pragma unroll
        for (int e = 0; e < 4; ++e) {
          rp[mi][e] += __shfl_xor(rp[mi][e], off);
          bp[mi][e] += __shfl_xor(bp[mi][e], off);
        }
    if (mr == 0) {
#pragma unroll
      for (int mi = 0; mi < 4; ++mi)
#pragma unroll
        for (int e = 0; e < 4; ++e) {
          atomicAdd(&j.nsq_out[m0 + lr0 + mi * 16 + kg * 4 + e], rp[mi][e]);
          atomicAdd(&j.bwd_out[m0 + lr0 + mi * 16 + kg * 4 + e], bp[mi][e]);
        }
    }
  } else {
    const float bbv = j.bb[j.which];
    float nv[4][4];
#pragma unroll
    for (int mi = 0; mi < 4; ++mi)
#pragma unroll
      for (int e = 0; e < 4; ++e) {
        const int r = m0 + lr0 + mi * 16 + kg * 4 + e;
        float tq = j.normsq[r] + 2.f * j.bwdot[r] + bbv;
        nv[mi][e] = 1.f / fmaxf(sqrtf(fmaxf(tq, 0.f)), 1e-12f);
      }
#pragma unroll
    for (int ni = 0; ni < 4; ++ni) {
      float blv = j.bl[n0 + lc0 + ni * 16 + mr];
      float mx = -3.0e38f;
#pragma unroll
      for (int mi = 0; mi < 4; ++mi)
#pragma unroll
        for (int e = 0; e < 4; ++e) mx = fmaxf(mx, (acc[mi][ni][e] + blv) * nv[mi][e]);
      atomicMax(&colkey[lc0 + ni * 16 + mr], fkey(mx));
    }
    __syncthreads();
    if (tid < 128) atomicMax(&j.skey[n0 + tid], colkey[tid]);
  }
}

// ---------------- fp32 pixel Gram: G2[m][n] = sum_c L[c][m]*R[c][n], 1024x1024, K=256 ----------------
__global__ __launch_bounds__(256) void k_pixgram(const float* __restrict__ L, const float* __restrict__ R,
                                                 float* __restrict__ G2) {
  __shared__ float As[16][32];
  __shared__ float Bs[16][32];
  const int tid = threadIdx.x;
  const int tx = tid & 15, ty = tid >> 4;
  const int m0 = blockIdx.y * 32, n0 = blockIdx.x * 32;
  float acc[2][2] = {};
  for (int kb = 0; kb < 256; kb += 16) {
    __syncthreads();
    {
      int kk = tid >> 5, mm = tid & 31;
      As[kk][mm] = L[(size_t)(kb + kk) * 1024 + m0 + mm];
      Bs[kk][mm] = R[(size_t)(kb + kk) * 1024 + n0 + mm];
      int e2 = tid + 256; int kk2 = e2 >> 5, mm2 = e2 & 31;
      As[kk2][mm2] = L[(size_t)(kb + kk2) * 1024 + m0 + mm2];
      Bs[kk2][mm2] = R[(size_t)(kb + kk2) * 1024 + n0 + mm2];
    }
    __syncthreads();
#pragma unroll
    for (int kk = 0; kk < 16; ++kk) {
      float a0 = As[kk][ty * 2], a1 = As[kk][ty * 2 + 1];
      float b0 = Bs[kk][tx * 2], b1 = Bs[kk][tx * 2 + 1];
      acc[0][0] = fmaf(a0, b0, acc[0][0]); acc[0][1] = fmaf(a0, b1, acc[0][1]);
      acc[1][0] = fmaf(a1, b0, acc[1][0]); acc[1][1] = fmaf(a1, b1, acc[1][1]);
    }
  }
#pragma unroll
  for (int i = 0; i < 2; ++i)
#pragma unroll
    for (int j = 0; j < 2; ++j)
      G2[(size_t)(m0 + ty * 2 + i) * 1024 + (n0 + tx * 2 + j)] = acc[i][j];
}

// ---------------- R3 max/argmax from pixel Gram via masked 9-point diagonal-shift sum ----------------
__global__ __launch_bounds__(256) void k_r3max(const float* __restrict__ G2, const float* __restrict__ scu3,
                                               const float* __restrict__ sclr,
                                               float* __restrict__ s3, int* __restrict__ arg) {
  const int m = blockIdx.x;
  const int mi = m >> 5, mj = m & 31;
  float best = -3.0e38f; int bi = 0;
  for (int n = threadIdx.x; n < 1024; n += 256) {
    const int ni = n >> 5, nj = n & 31;
    float raw = 0.f;
#pragma unroll
    for (int dy = -1; dy <= 1; ++dy) {
#pragma unroll
      for (int dx = -1; dx <= 1; ++dx) {
        bool vm = ((unsigned)(mi + dy) < 32u) && ((unsigned)(mj + dx) < 32u);
        bool vn = ((unsigned)(ni + dy) < 32u) && ((unsigned)(nj + dx) < 32u);
        if (vm && vn) {
          int off = dy * 32 + dx;
          raw += G2[(size_t)(m + off) * 1024 + (n + off)];
        }
      }
    }
    float v = raw * scu3[n];
    if (v > best) { best = v; bi = n; }
  }
  __shared__ float bv[256]; __shared__ int bidx[256];
  bv[threadIdx.x] = best; bidx[threadIdx.x] = bi;
  __syncthreads();
  for (int o = 128; o > 0; o >>= 1) {
    if (threadIdx.x < o) {
      float ov = bv[threadIdx.x + o]; int oi = bidx[threadIdx.x + o];
      if (ov > bv[threadIdx.x] || (ov == bv[threadIdx.x] && oi < bidx[threadIdx.x])) {
        bv[threadIdx.x] = ov; bidx[threadIdx.x] = oi;
      }
    }
    __syncthreads();
  }
  if (threadIdx.x == 0) { s3[m] = bv[0] * sclr[m]; arg[m] = bidx[0]; }
}

__global__ __launch_bounds__(256) void k_finS(const unsigned* __restrict__ k1, const unsigned* __restrict__ k2, float* __restrict__ out) {
  int t = blockIdx.x * 256 + threadIdx.x;
  if (t < 1024) { out[t] = kdec(k1[t]); out[1024 + t] = kdec(k2[t]); }
}

// ---------------- gather + fold ----------------
__global__ __launch_bounds__(256) void k_tfold3(const float* __restrict__ ref, const int* __restrict__ arg, float* __restrict__ out) {
  int id = blockIdx.x * 256 + threadIdx.x;
  int c = id >> 10, rem = id & 1023;
  int y = rem >> 5, x = rem & 31;
  float s = 0.f;
#pragma unroll
  for (int ki = 0; ki < 3; ++ki) {
    int i = y + 1 - ki;
    if ((unsigned)i >= 32u) continue;
#pragma unroll
    for (int kj = 0; kj < 3; ++kj) {
      int j = x + 1 - kj;
      if ((unsigned)j >= 32u) continue;
      int n2 = arg[i * 32 + j];
      int rr = (n2 >> 5) + ki - 1, cc = (n2 & 31) + kj - 1;
      if ((unsigned)rr < 32u && (unsigned)cc < 32u) s += ref[(size_t)c * 1024 + rr * 32 + cc];
    }
  }
  out[id] = s * (1.f / 9.f);
}
__global__ __launch_bounds__(256) void k_tfold2(const float* __restrict__ ref, const int* __restrict__ arg, float* __restrict__ out) {
  int id = blockIdx.x * 256 + threadIdx.x;
  int c = id >> 12, rem = id & 4095;
  int y = rem >> 6, x = rem & 63;
  float s = 0.f;
#pragma unroll
  for (int ki = 0; ki < 6; ++ki) {
    int t = y + 2 - ki;
    if (t < 0 || (t & 1)) continue;
    int i = t >> 1;
    if (i >= 32) continue;
#pragma unroll
    for (int kj = 0; kj < 6; ++kj) {
      int t2 = x + 2 - kj;
      if (t2 < 0 || (t2 & 1)) continue;
      int j = t2 >> 1;
      if (j >= 32) continue;
      int n2 = arg[i * 32 + j];
      int rr = (n2 >> 5) * 2 + ki - 2, cc = (n2 & 31) * 2 + kj - 2;
      if ((unsigned)rr < 64u && (unsigned)cc < 64u) s += ref[(size_t)c * 4096 + rr * 64 + cc];
    }
  }
  out[id] = s * (1.f / 9.f);
}
__global__ __launch_bounds__(256) void k_tfold1(const float* __restrict__ ref, const int* __restrict__ arg, float* __restrict__ out) {
  int id = blockIdx.x * 256 + threadIdx.x;
  int c = id >> 14, rem = id & 16383;
  int y = rem >> 7, x = rem & 127;
  float s = 0.f;
#pragma unroll
  for (int ki = 0; ki < 12; ++ki) {
    int t = y + 4 - ki;
    if (t < 0 || (t & 3)) continue;
    int i = t >> 2;
    if (i >= 32) continue;
#pragma unroll
    for (int kj = 0; kj < 12; ++kj) {
      int t2 = x + 4 - kj;
      if (t2 < 0 || (t2 & 3)) continue;
      int j = t2 >> 2;
      if (j >= 32) continue;
      int n2 = arg[i * 32 + j];
      int rr = (n2 >> 5) * 4 + ki - 4, cc = (n2 & 31) * 4 + kj - 4;
      if ((unsigned)rr < 128u && (unsigned)cc < 128u) s += ref[(size_t)c * 16384 + rr * 128 + cc];
    }
  }
  out[id] = s * (1.f / 9.f);
}

// ---------------- workspace layout (bytes) ----------------
// zero-initialized region (memset each launch):
static constexpr size_t OFF_NORMSQ2 = 0;              // 4096 f32
static constexpr size_t OFF_NORMSQ1 = 16384;          // 16384 f32
static constexpr size_t OFF_BWD2    = 81920;          // 4096 f32
static constexpr size_t OFF_BWD1    = 98304;          // 16384 f32
static constexpr size_t OFF_S1KEY   = 163840;         // 1024 u32
static constexpr size_t OFF_S2KEY   = 167936;         // 1024 u32
static constexpr size_t OFF_BW2     = 172032;         // 1152 f32
static constexpr size_t OFF_BW1     = 176640;         // 640 f32
static constexpr size_t ZERO_BYTES  = 179200;
// non-zeroed:
static constexpr size_t OFF_BL2     = 179200;                   // f32 [1024]
static constexpr size_t OFF_BL1     = 183296;                   // f32 [1024]
static constexpr size_t OFF_LR3NBT  = 187392;                   // bf16 [1024][2304]
static constexpr size_t OFF_U2B     = OFF_LR3NBT + 4718592;     // bf16 [4096][1152]
static constexpr size_t OFF_U1B     = OFF_U2B    + 9437184;     // bf16 [16384][640] (cols 576+ zero)
static constexpr size_t OFF_W1T     = OFF_U1B    + 20971520;    // bf16 [1152][2304]
static constexpr size_t OFF_W2T     = OFF_W1T    + 5308416;     // bf16 [640][2304] (rows 576+ zero)
static constexpr size_t OFF_A2      = OFF_W2T    + 2949120;     // bf16 [1152][1152]
static constexpr size_t OFF_A1      = OFF_A2     + 2654208;     // bf16 [640][640]
static constexpr size_t OFF_M2T     = OFF_A1     + 819200;      // bf16 [1024][1152]
static constexpr size_t OFF_M1T     = OFF_M2T    + 2359296;     // bf16 [1024][640]
static constexpr size_t OFF_G2      = OFF_M1T    + 1310720;     // f32 [1024][1024]
static constexpr size_t OFF_R3ARG   = OFF_G2     + 4194304;     // int [1024]
static constexpr size_t OFF_SCLR    = OFF_R3ARG  + 4096;        // f32 [1024]
static constexpr size_t OFF_SCU3    = OFF_SCLR   + 4096;        // f32 [1024]
static constexpr size_t OFF_BB      = OFF_SCU3   + 4096;        // f32 [2]

extern "C" void kernel_launch(void* const* d_in, const int* in_sizes, int n_in,
                              void* d_out, int out_size, void* d_ws, size_t ws_size,
                              hipStream_t stream) {
  (void)in_sizes; (void)n_in; (void)out_size; (void)ws_size;
  const float* lrsr3  = (const float*)d_in[0];
  const float* rsr1   = (const float*)d_in[1];
  const float* rsr2   = (const float*)d_in[2];
  const float* rsr3   = (const float*)d_in[3];
  const float* ref1   = (const float*)d_in[4];
  const float* ref2   = (const float*)d_in[5];
  const float* ref3   = (const float*)d_in[6];
  const float* W1     = (const float*)d_in[7];
  const float* b1     = (const float*)d_in[8];
  const float* W2     = (const float*)d_in[9];
  const float* b2     = (const float*)d_in[10];
  float* out = (float*)d_out;
  char* ws = (char*)d_ws;

  float*          normsq2 = (float*)(ws + OFF_NORMSQ2);
  float*          normsq1 = (float*)(ws + OFF_NORMSQ1);
  float*          bwd2    = (float*)(ws + OFF_BWD2);
  float*          bwd1    = (float*)(ws + OFF_BWD1);
  unsigned*       s1key   = (unsigned*)(ws + OFF_S1KEY);
  unsigned*       s2key   = (unsigned*)(ws + OFF_S2KEY);
  float*          bw2     = (float*)(ws + OFF_BW2);
  float*          bw1     = (float*)(ws + OFF_BW1);
  float*          bl2     = (float*)(ws + OFF_BL2);
  float*          bl1     = (float*)(ws + OFF_BL1);
  unsigned short* lr3nbT  = (unsigned short*)(ws + OFF_LR3NBT);
  unsigned short* U2b     = (unsigned short*)(ws + OFF_U2B);
  unsigned short* U1b     = (unsigned short*)(ws + OFF_U1B);
  unsigned short* W1t     = (unsigned short*)(ws + OFF_W1T);
  unsigned short* W2t     = (unsigned short*)(ws + OFF_W2T);
  unsigned short* A2b     = (unsigned short*)(ws + OFF_A2);
  unsigned short* A1b     = (unsigned short*)(ws + OFF_A1);
  unsigned short* M2tb    = (unsigned short*)(ws + OFF_M2T);
  unsigned short* M1tb    = (unsigned short*)(ws + OFF_M1T);
  float*          G2      = (float*)(ws + OFF_G2);
  int*            R3arg   = (int*)(ws + OFF_R3ARG);
  float*          sclr    = (float*)(ws + OFF_SCLR);
  float*          scu3    = (float*)(ws + OFF_SCU3);
  float*          bb      = (float*)(ws + OFF_BB);

  hipMemsetAsync(d_ws, 0, ZERO_BYTES, stream);
  // zero pad rows 576..639 of W2t
  hipMemsetAsync(ws + OFF_W2T + (size_t)576 * 2304 * 2, 0, (size_t)64 * 2304 * 2, stream);

  // norms + bias dots + pixel Gram (R3 path, all fp32, no unfold materialization)
  k_colnorm_bl<<<1024, 256, 0, stream>>>(lrsr3, b1, b2, sclr, bl2, bl1);
  k_colnorm<<<1024, 256, 0, stream>>>(rsr3, scu3);
  k_pixgram<<<dim3(32, 32), 256, 0, stream>>>(lrsr3, rsr3, G2);
  k_r3max<<<1024, 256, 0, stream>>>(G2, scu3, sclr, out + 2048, R3arg);

  // unfolds / transposes for the bf16 score paths
  k_pass2_md_bf<<<9216, 256, 0, stream>>>(lrsr3, sclr, lr3nbT);
  k_unfold_bf<<<18432, 256, 0, stream>>>(rsr2, U2b, 6, 1152, 1152, 4096 * 1152);
  k_unfold_bf<<<40960, 256, 0, stream>>>(rsr1, U1b, 7, 640, 576, 16384 * 640);
  k_wtransT<<<dim3(18, 36), 256, 0, stream>>>(W1, W1t, 1152);
  k_wtransT<<<dim3(9, 36), 256, 0, stream>>>(W2, W2t, 576);
  k_bw<<<dim3(5, 9), 256, 0, stream>>>(W1, b1, bw2, 1152);
  k_bw<<<dim3(3, 9), 256, 0, stream>>>(W2, b2, bw1, 576);
  k_bb<<<2, 256, 0, stream>>>(b1, b2, bb);

  Job jz = {};

  // P: Gram matrices + M^T, fused across row-concat [Wt ; lr3nbT]
  {
    Job a = jz, b = jz;
    a.Alo = W1t; a.Ahi = lr3nbT; a.Msplit = 1152; a.Bt = W1t;
    a.Clo = A2b; a.Chi = M2tb; a.N = 1152; a.K = 2304; a.nbx = 9;
    b.Alo = W2t; b.Ahi = lr3nbT; b.Msplit = 640; b.Bt = W2t;
    b.Clo = A1b; b.Chi = M1tb; b.N = 640; b.K = 2304; b.nbx = 5;
    k_gemm128<0><<<153 + 65, 256, 0, stream>>>(a, b, 153);
  }
  // E1: norms + bw dots via Gram quadratic form
  {
    Job a = jz, b = jz;
    a.Alo = U2b; a.Ahi = U2b; a.Msplit = 4096; a.Bt = A2b;
    a.bw = bw2; a.nsq_out = normsq2; a.bwd_out = bwd2; a.N = 1152; a.K = 1152; a.nbx = 9;
    b.Alo = U1b; b.Ahi = U1b; b.Msplit = 16384; b.Bt = A1b;
    b.bw = bw1; b.nsq_out = normsq1; b.bwd_out = bwd1; b.N = 640; b.K = 640; b.nbx = 5;
    k_gemm128<1><<<288 + 640, 256, 0, stream>>>(a, b, 288);
  }
  // E2: score max S = max_n (U@M^T + bl)/norm  (ninv computed inline)
  {
    Job a = jz, b = jz;
    a.Alo = U2b; a.Ahi = U2b; a.Msplit = 4096; a.Bt = M2tb;
    a.bl = bl2; a.normsq = normsq2; a.bwdot = bwd2; a.bb = bb; a.which = 0;
    a.skey = s2key; a.N = 1024; a.K = 1152; a.nbx = 8;
    b.Alo = U1b; b.Ahi = U1b; b.Msplit = 16384; b.Bt = M1tb;
    b.bl = bl1; b.normsq = normsq1; b.bwdot = bwd1; b.bb = bb; b.which = 1;
    b.skey = s1key; b.N = 1024; b.K = 640; b.nbx = 8;
    k_gemm128<2><<<256 + 1024, 256, 0, stream>>>(a, b, 256);
  }

  k_finS<<<4, 256, 0, stream>>>(s1key, s2key, out);

  // transfer: gather chosen columns and fold
  k_tfold3<<<1024, 256, 0, stream>>>(ref3, R3arg, out + 3072);
  k_tfold2<<<2048, 256, 0, stream>>>(ref2, R3arg, out + 265216);
  k_tfold1<<<4096, 256, 0, stream>>>(ref1, R3arg, out + 789504);
}

// Round 6
// 346.724 us; speedup vs baseline: 2.4310x; 1.0310x over previous
//
#include <hip/hip_runtime.h>

typedef short bf8 __attribute__((ext_vector_type(8)));
typedef float f32x4 __attribute__((ext_vector_type(4)));

static __device__ __forceinline__ unsigned short f2bf(float f) {
  unsigned u = __float_as_uint(f);
  unsigned r = u + 0x7FFFu + ((u >> 16) & 1u);
  return (unsigned short)(r >> 16);
}
static __device__ __forceinline__ float bf2f(unsigned short h) {
  return __uint_as_float(((unsigned)h) << 16);
}
static __device__ __forceinline__ unsigned fkey(float f) {
  unsigned u = __float_as_uint(f);
  return (u & 0x80000000u) ? ~u : (u | 0x80000000u);
}
static __device__ __forceinline__ float kdec(unsigned k) {
  unsigned u = (k & 0x80000000u) ? (k & 0x7FFFFFFFu) : ~k;
  return __uint_as_float(u);
}

// async global->LDS, 16B per lane. lds dest: wave-uniform base + lane*16.
static __device__ __forceinline__ void gload_lds16(const unsigned short* g, unsigned short* l) {
  __builtin_amdgcn_global_load_lds((const __attribute__((address_space(1))) void*)g,
                                   (__attribute__((address_space(3))) void*)l, 16, 0, 0);
}

// unfold(k=3,pad=1,stride=1) value: row d = (cc*3+ki)*3+kj, col m = i*S+j, src [C][S][S]
static __device__ __forceinline__ float uf3(const float* __restrict__ src, int lgS, int d, int m) {
  const int S = 1 << lgS;
  int cc = d / 9;
  int r9 = d - cc * 9;
  int ki = r9 / 3;
  int kj = r9 - ki * 3;
  int i = (m >> lgS) + ki - 1;
  int j = (m & (S - 1)) + kj - 1;
  if ((unsigned)i >= (unsigned)S || (unsigned)j >= (unsigned)S) return 0.f;
  return src[((size_t)cc << (2 * lgS)) + ((size_t)i << lgS) + j];
}

// ---------------- prep kernels (fused) ----------------

// blocks [0,1024): colnorm+bias-dots of lrsr3 -> sclr, bl2, bl1. blocks [1024,2048): colnorm of rsr3 -> scu3.
__global__ __launch_bounds__(256) void k_colnorm2(const float* __restrict__ lrsr3, const float* __restrict__ rsr3,
                                                  const float* __restrict__ b1, const float* __restrict__ b2,
                                                  float* __restrict__ sclr, float* __restrict__ scu3,
                                                  float* __restrict__ bl2, float* __restrict__ bl1) {
  const bool lr = blockIdx.x < 1024;
  const int m = blockIdx.x & 1023;
  const float* src = lr ? lrsr3 : rsr3;
  float s = 0.f, d1 = 0.f, d2 = 0.f;
  for (int d = threadIdx.x; d < 2304; d += 256) {
    float v = uf3(src, 5, d, m);
    s += v * v; d1 += b1[d] * v; d2 += b2[d] * v;
  }
  __shared__ float r0[256], r1[256], r2[256];
  r0[threadIdx.x] = s; r1[threadIdx.x] = d1; r2[threadIdx.x] = d2;
  __syncthreads();
  for (int o = 128; o > 0; o >>= 1) {
    if (threadIdx.x < o) {
      r0[threadIdx.x] += r0[threadIdx.x + o];
      r1[threadIdx.x] += r1[threadIdx.x + o];
      r2[threadIdx.x] += r2[threadIdx.x + o];
    }
    __syncthreads();
  }
  if (threadIdx.x == 0) {
    float sc = 1.f / fmaxf(sqrtf(r0[0]), 1e-12f);
    if (lr) { sclr[m] = sc; bl2[m] = r1[0] * sc; bl1[m] = r2[0] * sc; }
    else    { scu3[m] = sc; }
  }
}

// normalized unfold, bf16, layout [m][d]
__global__ __launch_bounds__(256) void k_pass2_md_bf(const float* __restrict__ src, const float* __restrict__ scale, unsigned short* __restrict__ out) {
  int id = blockIdx.x * 256 + threadIdx.x;
  int m = id / 2304, d = id - m * 2304;
  out[id] = f2bf(uf3(src, 5, d, m) * scale[m]);
}

// fused unfolds: blocks [0,18432): rsr2 -> U2b [4096][1152]; rest: rsr1 -> U1b [16384][640] (cols 576+ zero)
__global__ __launch_bounds__(256) void k_unfold2(const float* __restrict__ rsr2, const float* __restrict__ rsr1,
                                                 unsigned short* __restrict__ U2b, unsigned short* __restrict__ U1b) {
  int bid = blockIdx.x;
  if (bid < 18432) {
    int id = bid * 256 + threadIdx.x;
    int n = id / 1152, c = id - n * 1152;
    U2b[id] = f2bf(uf3(rsr2, 6, c, n));
  } else {
    int id = (bid - 18432) * 256 + threadIdx.x;
    int n = id / 640, c = id - n * 640;
    float v = (c < 576) ? uf3(rsr1, 7, c, n) : 0.f;
    U1b[id] = f2bf(v);
  }
}

// fused W transposes, LDS-tiled 64x64: blocks x<18 -> W1 (Cw=1152), else W2 (Cw=576)
__global__ __launch_bounds__(256) void k_wtrans2(const float* __restrict__ W1, const float* __restrict__ W2,
                                                 unsigned short* __restrict__ W1t, unsigned short* __restrict__ W2t) {
  __shared__ unsigned short Ls[64][65];
  const float* W; unsigned short* Wt; int Cw, c0;
  if (blockIdx.x < 18) { W = W1; Wt = W1t; Cw = 1152; c0 = blockIdx.x * 64; }
  else                 { W = W2; Wt = W2t; Cw = 576;  c0 = (blockIdx.x - 18) * 64; }
  const int d0 = blockIdx.y * 64;
#pragma unroll
  for (int i = 0; i < 16; ++i) {
    int idx = threadIdx.x + i * 256;
    int r = idx >> 6, c = idx & 63;
    Ls[r][c] = f2bf(W[(size_t)(d0 + r) * Cw + c0 + c]);
  }
  __syncthreads();
#pragma unroll
  for (int i = 0; i < 16; ++i) {
    int idx = threadIdx.x + i * 256;
    int cc = idx >> 6, rr = idx & 63;
    Wt[(size_t)(c0 + cc) * 2304 + d0 + rr] = Ls[rr][cc];
  }
}

// fused bw dots + bb: grid (8,10). y<9: x<5 -> bw2 chunk, x in [5,8) -> bw1 chunk. y==9: x==0 -> bb[0], x==1 -> bb[1].
__global__ __launch_bounds__(256) void k_bwbb(const float* __restrict__ W1, const float* __restrict__ W2,
                                              const float* __restrict__ b1, const float* __restrict__ b2,
                                              float* __restrict__ bw2, float* __restrict__ bw1,
                                              float* __restrict__ bb) {
  if (blockIdx.y == 9) {
    if (blockIdx.x >= 2) return;
    const float* b = blockIdx.x ? b2 : b1;
    float s = 0.f;
    for (int d = threadIdx.x; d < 2304; d += 256) s += b[d] * b[d];
    __shared__ float red[256];
    red[threadIdx.x] = s; __syncthreads();
    for (int o = 128; o > 0; o >>= 1) { if (threadIdx.x < o) red[threadIdx.x] += red[threadIdx.x + o]; __syncthreads(); }
    if (threadIdx.x == 0) bb[blockIdx.x] = red[0];
    return;
  }
  const bool two = blockIdx.x < 5;
  const float* W = two ? W1 : W2;
  const float* b = two ? b1 : b2;
  float* bw = two ? bw2 : bw1;
  const int Cw = two ? 1152 : 576;
  int c = (two ? blockIdx.x : blockIdx.x - 5) * 256 + threadIdx.x;
  if (c >= Cw) return;
  int d0 = blockIdx.y * 256;
  float s = 0.f;
  for (int d = d0; d < d0 + 256; ++d) s += b[d] * W[(size_t)d * Cw + c];
  atomicAdd(&bw[c], s);
}

// ---------------- bf16 MFMA GEMM: 128x128 tile, BK=64, 4 waves, counted-vmcnt pipeline, XCD-chunked ----------------
// TN form: C[i][j] = sum_k A[i][k]*Bt[j][k].  Rows split across two source/dest buffers at Msplit.
// Two jobs per dispatch (logical id < nb0 -> j0). K % 64 == 0, K >= 128.
// EPI 0: store bf16 C
// EPI 1: nsq_out[i] += sum_j C[i][j]*A[i][j]; bwd_out[i] += sum_j bw[j]*A[i][j]  (N==K; Bt symmetric Gram)
// EPI 2: skey[j] = max_i fkey((C[i][j]+bl[j]) / max(sqrt(max(normsq[i]+2*bwdot[i]+bb[which],0)),eps))
struct Job {
  const unsigned short* Alo;
  const unsigned short* Ahi;
  const unsigned short* Bt;
  unsigned short* Clo;
  unsigned short* Chi;
  const float* bl;
  const float* normsq;
  const float* bwdot;
  const float* bb;
  const float* bw;
  float* nsq_out;
  float* bwd_out;
  unsigned* skey;
  int Msplit, N, K, nbx, which;
};

template <int EPI>
__global__ __launch_bounds__(256) void k_gemm128(Job j0, Job j1, int nb0) {
  __shared__ __align__(16) unsigned short As[2][128 * 64];
  __shared__ __align__(16) unsigned short Bs[2][128 * 64];
  __shared__ unsigned colkey[128];

  // bijective XCD-chunked swizzle (m204): hw round-robins blockIdx across 8 XCDs;
  // map so each XCD owns a CONTIGUOUS run of logical blocks (= whole A row-panels).
  const int nwg = (int)gridDim.x;
  const int h = (int)blockIdx.x;
  const int qq = nwg >> 3, rm = nwg & 7;
  const int xcd = h & 7, wth = h >> 3;
  const int bid = (xcd < rm ? xcd * (qq + 1) : rm * (qq + 1) + (xcd - rm) * qq) + wth;

  const bool first = (bid < nb0);
  const Job j = first ? j0 : j1;
  const int local = bid - (first ? 0 : nb0);
  const int by = local / j.nbx;
  const int bx = local - by * j.nbx;
  const int m0 = by * 128, n0 = bx * 128;
  const int K = j.K, N = j.N;

  const unsigned short* Abase = (m0 < j.Msplit)
      ? j.Alo + (size_t)m0 * K
      : j.Ahi + (size_t)(m0 - j.Msplit) * K;

  const int tid = threadIdx.x;
  const int l = tid & 63;
  const int w = tid >> 6;          // wave 0..3
  const int wr = w >> 1, wc = w & 1;
  if (EPI == 2 && tid < 128) colkey[tid] = 0u;

  f32x4 acc[4][4] = {};

  // staging: wave w stages rows [w*32, w*32+32) in 4 chunks of 8 rows.
  // HW writes lane l at ldsbase + l*16B -> (row chunk+l>>3, slot l&7).
  // Pre-swizzle GLOBAL source so LDS slot q of row r holds global slot q^(r&7).
  const int srow = w * 32;
  const int lrow = l >> 3;
  const int gcol = ((l & 7) ^ lrow) * 8;
  const int mr = l & 15;
  const int kg = l >> 4;

  const int nt = K >> 6;
  const int snap_kb = n0 + wc * 64;
  unsigned short snap[4][4][4];

  auto stage = [&](int buf, int kb) {
#pragma unroll
    for (int i = 0; i < 4; ++i) {
      int r = srow + i * 8;
      gload_lds16(Abase + (size_t)(r + lrow) * K + kb + gcol, &As[buf][r * 64]);
      gload_lds16(j.Bt + (size_t)(n0 + r + lrow) * K + kb + gcol, &Bs[buf][r * 64]);
    }
  };

  // prologue: tiles 0 and 1 in flight; wait tile 0 (8 newest stay outstanding)
  stage(0, 0);
  stage(1, 64);
  asm volatile("s_waitcnt vmcnt(8)\ns_barrier" ::: "memory");

  int cur = 0;
  for (int t = 0; t < nt; ++t) {
#pragma unroll
    for (int ks = 0; ks < 2; ++ks) {
      bf8 af[4], bv[4];
#pragma unroll
      for (int mi = 0; mi < 4; ++mi) {
        const int row = wr * 64 + mi * 16 + mr;
        af[mi] = *(const bf8*)&As[cur][row * 64 + (((ks * 4 + kg) ^ (row & 7)) * 8)];
      }
#pragma unroll
      for (int ni = 0; ni < 4; ++ni) {
        const int row = wc * 64 + ni * 16 + mr;
        bv[ni] = *(const bf8*)&Bs[cur][row * 64 + (((ks * 4 + kg) ^ (row & 7)) * 8)];
      }
#pragma unroll
      for (int mi = 0; mi < 4; ++mi)
#pragma unroll
        for (int ni = 0; ni < 4; ++ni)
          acc[mi][ni] = __builtin_amdgcn_mfma_f32_16x16x32_bf16(af[mi], bv[ni], acc[mi][ni], 0, 0, 0);
    }
    if (EPI == 1 && (t << 6) == snap_kb) {
      // snapshot A values this lane's accumulator rows/cols need (quadratic form + bw dot)
#pragma unroll
      for (int mi = 0; mi < 4; ++mi)
#pragma unroll
        for (int e = 0; e < 4; ++e) {
          const int row = wr * 64 + mi * 16 + kg * 4 + e;
#pragma unroll
          for (int ni = 0; ni < 4; ++ni) {
            const int slot = ni * 2 + (mr >> 3);
            snap[mi][ni][e] = As[cur][row * 64 + ((slot ^ (row & 7)) * 8) + (mr & 7)];
          }
        }
    }
    if (t + 1 < nt) {
      asm volatile("s_waitcnt lgkmcnt(0)\ns_barrier" ::: "memory");   // buf[cur] free everywhere
      if (t + 2 < nt) {
        stage(cur, (t + 2) << 6);                                     // refill freed buffer
        asm volatile("s_waitcnt vmcnt(8)\ns_barrier" ::: "memory");   // tile t+1 landed; t+2 in flight
      } else {
        asm volatile("s_waitcnt vmcnt(0)\ns_barrier" ::: "memory");   // drain last prefetch
      }
      cur ^= 1;
    }
  }

  // C/D frag layout: col = mr, row = kg*4 + e (within 16x16)
  const int lr0 = wr * 64;         // + mi*16 + kg*4 + e (tile-relative row)
  const int lc0 = wc * 64;         // + ni*16 + mr       (tile-relative col)
  if (EPI == 0) {
    unsigned short* Cbase = (m0 < j.Msplit)
        ? j.Clo + (size_t)m0 * N
        : j.Chi + (size_t)(m0 - j.Msplit) * N;
#pragma unroll
    for (int mi = 0; mi < 4; ++mi)
#pragma unroll
      for (int ni = 0; ni < 4; ++ni)
#pragma unroll
        for (int e = 0; e < 4; ++e)
          Cbase[(size_t)(lr0 + mi * 16 + kg * 4 + e) * (size_t)N + (n0 + lc0 + ni * 16 + mr)] = f2bf(acc[mi][ni][e]);
  } else if (EPI == 1) {
    float rp[4][4] = {};
    float bp[4][4] = {};
#pragma unroll
    for (int ni = 0; ni < 4; ++ni) {
      const float bwv = j.bw[n0 + lc0 + ni * 16 + mr];
#pragma unroll
      for (int mi = 0; mi < 4; ++mi)
#pragma unroll
        for (int e = 0; e < 4; ++e) {
          const float av = bf2f(snap[mi][ni][e]);
          rp[mi][e] += acc[mi][ni][e] * av;
          bp[mi][e] += bwv * av;
        }
    }
#pragma unroll
    for (int off = 1; off < 16; off <<= 1)
#pragma unroll
      for (int mi = 0; mi < 4; ++mi)
#pragma unroll
        for (int e = 0; e < 4; ++e) {
          rp[mi][e] += __shfl_xor(rp[mi][e], off);
          bp[mi][e] += __shfl_xor(bp[mi][e], off);
        }
    if (mr == 0) {
#pragma unroll
      for (int mi = 0; mi < 4; ++mi)
#pragma unroll
        for (int e = 0; e < 4; ++e) {
          atomicAdd(&j.nsq_out[m0 + lr0 + mi * 16 + kg * 4 + e], rp[mi][e]);
          atomicAdd(&j.bwd_out[m0 + lr0 + mi * 16 + kg * 4 + e], bp[mi][e]);
        }
    }
  } else {
    const float bbv = j.bb[j.which];
    float nv[4][4];
#pragma unroll
    for (int mi = 0; mi < 4; ++mi)
#pragma unroll
      for (int e = 0; e < 4; ++e) {
        const int r = m0 + lr0 + mi * 16 + kg * 4 + e;
        float tq = j.normsq[r] + 2.f * j.bwdot[r] + bbv;
        nv[mi][e] = 1.f / fmaxf(sqrtf(fmaxf(tq, 0.f)), 1e-12f);
      }
#pragma unroll
    for (int ni = 0; ni < 4; ++ni) {
      float blv = j.bl[n0 + lc0 + ni * 16 + mr];
      float mx = -3.0e38f;
#pragma unroll
      for (int mi = 0; mi < 4; ++mi)
#pragma unroll
        for (int e = 0; e < 4; ++e) mx = fmaxf(mx, (acc[mi][ni][e] + blv) * nv[mi][e]);
      atomicMax(&colkey[lc0 + ni * 16 + mr], fkey(mx));
    }
    __syncthreads();
    if (tid < 128) atomicMax(&j.skey[n0 + tid], colkey[tid]);
  }
}

// ---------------- fp32 pixel Gram: G2[m][n] = sum_c L[c][m]*R[c][n], 1024x1024, K=256 ----------------
__global__ __launch_bounds__(256) void k_pixgram(const float* __restrict__ L, const float* __restrict__ R,
                                                 float* __restrict__ G2) {
  __shared__ float As[16][32];
  __shared__ float Bs[16][32];
  const int tid = threadIdx.x;
  const int tx = tid & 15, ty = tid >> 4;
  const int m0 = blockIdx.y * 32, n0 = blockIdx.x * 32;
  float acc[2][2] = {};
  for (int kb = 0; kb < 256; kb += 16) {
    __syncthreads();
    {
      int kk = tid >> 5, mm = tid & 31;
      As[kk][mm] = L[(size_t)(kb + kk) * 1024 + m0 + mm];
      Bs[kk][mm] = R[(size_t)(kb + kk) * 1024 + n0 + mm];
      int e2 = tid + 256; int kk2 = e2 >> 5, mm2 = e2 & 31;
      As[kk2][mm2] = L[(size_t)(kb + kk2) * 1024 + m0 + mm2];
      Bs[kk2][mm2] = R[(size_t)(kb + kk2) * 1024 + n0 + mm2];
    }
    __syncthreads();
#pragma unroll
    for (int kk = 0; kk < 16; ++kk) {
      float a0 = As[kk][ty * 2], a1 = As[kk][ty * 2 + 1];
      float b0 = Bs[kk][tx * 2], b1 = Bs[kk][tx * 2 + 1];
      acc[0][0] = fmaf(a0, b0, acc[0][0]); acc[0][1] = fmaf(a0, b1, acc[0][1]);
      acc[1][0] = fmaf(a1, b0, acc[1][0]); acc[1][1] = fmaf(a1, b1, acc[1][1]);
    }
  }
#pragma unroll
  for (int i = 0; i < 2; ++i)
#pragma unroll
    for (int j = 0; j < 2; ++j)
      G2[(size_t)(m0 + ty * 2 + i) * 1024 + (n0 + tx * 2 + j)] = acc[i][j];
}

// ---------------- R3 max/argmax from pixel Gram via masked 9-point diagonal-shift sum ----------------
__global__ __launch_bounds__(256) void k_r3max(const float* __restrict__ G2, const float* __restrict__ scu3,
                                               const float* __restrict__ sclr,
                                               float* __restrict__ s3, int* __restrict__ arg) {
  const int m = blockIdx.x;
  const int mi = m >> 5, mj = m & 31;
  float best = -3.0e38f; int bi = 0;
  for (int n = threadIdx.x; n < 1024; n += 256) {
    const int ni = n >> 5, nj = n & 31;
    float raw = 0.f;
#pragma unroll
    for (int dy = -1; dy <= 1; ++dy) {
#pragma unroll
      for (int dx = -1; dx <= 1; ++dx) {
        bool vm = ((unsigned)(mi + dy) < 32u) && ((unsigned)(mj + dx) < 32u);
        bool vn = ((unsigned)(ni + dy) < 32u) && ((unsigned)(nj + dx) < 32u);
        if (vm && vn) {
          int off = dy * 32 + dx;
          raw += G2[(size_t)(m + off) * 1024 + (n + off)];
        }
      }
    }
    float v = raw * scu3[n];
    if (v > best) { best = v; bi = n; }
  }
  __shared__ float bv[256]; __shared__ int bidx[256];
  bv[threadIdx.x] = best; bidx[threadIdx.x] = bi;
  __syncthreads();
  for (int o = 128; o > 0; o >>= 1) {
    if (threadIdx.x < o) {
      float ov = bv[threadIdx.x + o]; int oi = bidx[threadIdx.x + o];
      if (ov > bv[threadIdx.x] || (ov == bv[threadIdx.x] && oi < bidx[threadIdx.x])) {
        bv[threadIdx.x] = ov; bidx[threadIdx.x] = oi;
      }
    }
    __syncthreads();
  }
  if (threadIdx.x == 0) { s3[m] = bv[0] * sclr[m]; arg[m] = bidx[0]; }
}

// ---------------- fused gather+fold + S1/S2 finalize ----------------
// blocks [0,1024): T3; [1024,3072): T2; [3072,7168): T1; [7168,7172): S1/S2 from keys
__global__ __launch_bounds__(256) void k_tfold(const float* __restrict__ ref3, const float* __restrict__ ref2,
                                               const float* __restrict__ ref1, const int* __restrict__ arg,
                                               const unsigned* __restrict__ s1key, const unsigned* __restrict__ s2key,
                                               float* __restrict__ out) {
  int bid = blockIdx.x;
  if (bid < 1024) {
    int id = bid * 256 + threadIdx.x;
    int c = id >> 10, rem = id & 1023;
    int y = rem >> 5, x = rem & 31;
    float s = 0.f;
#pragma unroll
    for (int ki = 0; ki < 3; ++ki) {
      int i = y + 1 - ki;
      if ((unsigned)i >= 32u) continue;
#pragma unroll
      for (int kj = 0; kj < 3; ++kj) {
        int j = x + 1 - kj;
        if ((unsigned)j >= 32u) continue;
        int n2 = arg[i * 32 + j];
        int rr = (n2 >> 5) + ki - 1, cc = (n2 & 31) + kj - 1;
        if ((unsigned)rr < 32u && (unsigned)cc < 32u) s += ref3[(size_t)c * 1024 + rr * 32 + cc];
      }
    }
    out[3072 + id] = s * (1.f / 9.f);
  } else if (bid < 3072) {
    int id = (bid - 1024) * 256 + threadIdx.x;
    int c = id >> 12, rem = id & 4095;
    int y = rem >> 6, x = rem & 63;
    float s = 0.f;
#pragma unroll
    for (int ki = 0; ki < 6; ++ki) {
      int t = y + 2 - ki;
      if (t < 0 || (t & 1)) continue;
      int i = t >> 1;
      if (i >= 32) continue;
#pragma unroll
      for (int kj = 0; kj < 6; ++kj) {
        int t2 = x + 2 - kj;
        if (t2 < 0 || (t2 & 1)) continue;
        int j = t2 >> 1;
        if (j >= 32) continue;
        int n2 = arg[i * 32 + j];
        int rr = (n2 >> 5) * 2 + ki - 2, cc = (n2 & 31) * 2 + kj - 2;
        if ((unsigned)rr < 64u && (unsigned)cc < 64u) s += ref2[(size_t)c * 4096 + rr * 64 + cc];
      }
    }
    out[265216 + id] = s * (1.f / 9.f);
  } else if (bid < 7168) {
    int id = (bid - 3072) * 256 + threadIdx.x;
    int c = id >> 14, rem = id & 16383;
    int y = rem >> 7, x = rem & 127;
    float s = 0.f;
#pragma unroll
    for (int ki = 0; ki < 12; ++ki) {
      int t = y + 4 - ki;
      if (t < 0 || (t & 3)) continue;
      int i = t >> 2;
      if (i >= 32) continue;
#pragma unroll
      for (int kj = 0; kj < 12; ++kj) {
        int t2 = x + 4 - kj;
        if (t2 < 0 || (t2 & 3)) continue;
        int j = t2 >> 2;
        if (j >= 32) continue;
        int n2 = arg[i * 32 + j];
        int rr = (n2 >> 5) * 4 + ki - 4, cc = (n2 & 31) * 4 + kj - 4;
        if ((unsigned)rr < 128u && (unsigned)cc < 128u) s += ref1[(size_t)c * 16384 + rr * 128 + cc];
      }
    }
    out[789504 + id] = s * (1.f / 9.f);
  } else {
    int t = (bid - 7168) * 256 + threadIdx.x;
    if (t < 1024) { out[t] = kdec(s1key[t]); out[1024 + t] = kdec(s2key[t]); }
  }
}

// ---------------- workspace layout (bytes) ----------------
// zero-initialized region (memset each launch):
static constexpr size_t OFF_NORMSQ2 = 0;              // 4096 f32
static constexpr size_t OFF_NORMSQ1 = 16384;          // 16384 f32
static constexpr size_t OFF_BWD2    = 81920;          // 4096 f32
static constexpr size_t OFF_BWD1    = 98304;          // 16384 f32
static constexpr size_t OFF_S1KEY   = 163840;         // 1024 u32
static constexpr size_t OFF_S2KEY   = 167936;         // 1024 u32
static constexpr size_t OFF_BW2     = 172032;         // 1152 f32
static constexpr size_t OFF_BW1     = 176640;         // 640 f32
static constexpr size_t ZERO_BYTES  = 179200;
// non-zeroed:
static constexpr size_t OFF_BL2     = 179200;                   // f32 [1024]
static constexpr size_t OFF_BL1     = 183296;                   // f32 [1024]
static constexpr size_t OFF_LR3NBT  = 187392;                   // bf16 [1024][2304]
static constexpr size_t OFF_U2B     = OFF_LR3NBT + 4718592;     // bf16 [4096][1152]
static constexpr size_t OFF_U1B     = OFF_U2B    + 9437184;     // bf16 [16384][640] (cols 576+ zero)
static constexpr size_t OFF_W1T     = OFF_U1B    + 20971520;    // bf16 [1152][2304]
static constexpr size_t OFF_W2T     = OFF_W1T    + 5308416;     // bf16 [640][2304] (rows 576+ zero)
static constexpr size_t OFF_A2      = OFF_W2T    + 2949120;     // bf16 [1152][1152]
static constexpr size_t OFF_A1      = OFF_A2     + 2654208;     // bf16 [640][640]
static constexpr size_t OFF_M2T     = OFF_A1     + 819200;      // bf16 [1024][1152]
static constexpr size_t OFF_M1T     = OFF_M2T    + 2359296;     // bf16 [1024][640]
static constexpr size_t OFF_G2      = OFF_M1T    + 1310720;     // f32 [1024][1024]
static constexpr size_t OFF_R3ARG   = OFF_G2     + 4194304;     // int [1024]
static constexpr size_t OFF_SCLR    = OFF_R3ARG  + 4096;        // f32 [1024]
static constexpr size_t OFF_SCU3    = OFF_SCLR   + 4096;        // f32 [1024]
static constexpr size_t OFF_BB      = OFF_SCU3   + 4096;        // f32 [2]

extern "C" void kernel_launch(void* const* d_in, const int* in_sizes, int n_in,
                              void* d_out, int out_size, void* d_ws, size_t ws_size,
                              hipStream_t stream) {
  (void)in_sizes; (void)n_in; (void)out_size; (void)ws_size;
  const float* lrsr3  = (const float*)d_in[0];
  const float* rsr1   = (const float*)d_in[1];
  const float* rsr2   = (const float*)d_in[2];
  const float* rsr3   = (const float*)d_in[3];
  const float* ref1   = (const float*)d_in[4];
  const float* ref2   = (const float*)d_in[5];
  const float* ref3   = (const float*)d_in[6];
  const float* W1     = (const float*)d_in[7];
  const float* b1     = (const float*)d_in[8];
  const float* W2     = (const float*)d_in[9];
  const float* b2     = (const float*)d_in[10];
  float* out = (float*)d_out;
  char* ws = (char*)d_ws;

  float*          normsq2 = (float*)(ws + OFF_NORMSQ2);
  float*          normsq1 = (float*)(ws + OFF_NORMSQ1);
  float*          bwd2    = (float*)(ws + OFF_BWD2);
  float*          bwd1    = (float*)(ws + OFF_BWD1);
  unsigned*       s1key   = (unsigned*)(ws + OFF_S1KEY);
  unsigned*       s2key   = (unsigned*)(ws + OFF_S2KEY);
  float*          bw2     = (float*)(ws + OFF_BW2);
  float*          bw1     = (float*)(ws + OFF_BW1);
  float*          bl2     = (float*)(ws + OFF_BL2);
  float*          bl1     = (float*)(ws + OFF_BL1);
  unsigned short* lr3nbT  = (unsigned short*)(ws + OFF_LR3NBT);
  unsigned short* U2b     = (unsigned short*)(ws + OFF_U2B);
  unsigned short* U1b     = (unsigned short*)(ws + OFF_U1B);
  unsigned short* W1t     = (unsigned short*)(ws + OFF_W1T);
  unsigned short* W2t     = (unsigned short*)(ws + OFF_W2T);
  unsigned short* A2b     = (unsigned short*)(ws + OFF_A2);
  unsigned short* A1b     = (unsigned short*)(ws + OFF_A1);
  unsigned short* M2tb    = (unsigned short*)(ws + OFF_M2T);
  unsigned short* M1tb    = (unsigned short*)(ws + OFF_M1T);
  float*          G2      = (float*)(ws + OFF_G2);
  int*            R3arg   = (int*)(ws + OFF_R3ARG);
  float*          sclr    = (float*)(ws + OFF_SCLR);
  float*          scu3    = (float*)(ws + OFF_SCU3);
  float*          bb      = (float*)(ws + OFF_BB);

  hipMemsetAsync(d_ws, 0, ZERO_BYTES, stream);
  // zero pad rows 576..639 of W2t
  hipMemsetAsync(ws + OFF_W2T + (size_t)576 * 2304 * 2, 0, (size_t)64 * 2304 * 2, stream);

  // norms + bias dots + pixel Gram (R3 path, all fp32, no unfold materialization)
  k_colnorm2<<<2048, 256, 0, stream>>>(lrsr3, rsr3, b1, b2, sclr, scu3, bl2, bl1);
  k_pixgram<<<dim3(32, 32), 256, 0, stream>>>(lrsr3, rsr3, G2);
  k_r3max<<<1024, 256, 0, stream>>>(G2, scu3, sclr, out + 2048, R3arg);

  // unfolds / transposes for the bf16 score paths
  k_pass2_md_bf<<<9216, 256, 0, stream>>>(lrsr3, sclr, lr3nbT);
  k_unfold2<<<59392, 256, 0, stream>>>(rsr2, rsr1, U2b, U1b);
  k_wtrans2<<<dim3(27, 36), 256, 0, stream>>>(W1, W2, W1t, W2t);
  k_bwbb<<<dim3(8, 10), 256, 0, stream>>>(W1, W2, b1, b2, bw2, bw1, bb);

  Job jz = {};

  // P: Gram matrices + M^T, fused across row-concat [Wt ; lr3nbT]
  {
    Job a = jz, b = jz;
    a.Alo = W1t; a.Ahi = lr3nbT; a.Msplit = 1152; a.Bt = W1t;
    a.Clo = A2b; a.Chi = M2tb; a.N = 1152; a.K = 2304; a.nbx = 9;
    b.Alo = W2t; b.Ahi = lr3nbT; b.Msplit = 640; b.Bt = W2t;
    b.Clo = A1b; b.Chi = M1tb; b.N = 640; b.K = 2304; b.nbx = 5;
    k_gemm128<0><<<153 + 65, 256, 0, stream>>>(a, b, 153);
  }
  // E1: norms + bw dots via Gram quadratic form
  {
    Job a = jz, b = jz;
    a.Alo = U2b; a.Ahi = U2b; a.Msplit = 4096; a.Bt = A2b;
    a.bw = bw2; a.nsq_out = normsq2; a.bwd_out = bwd2; a.N = 1152; a.K = 1152; a.nbx = 9;
    b.Alo = U1b; b.Ahi = U1b; b.Msplit = 16384; b.Bt = A1b;
    b.bw = bw1; b.nsq_out = normsq1; b.bwd_out = bwd1; b.N = 640; b.K = 640; b.nbx = 5;
    k_gemm128<1><<<288 + 640, 256, 0, stream>>>(a, b, 288);
  }
  // E2: score max S = max_n (U@M^T + bl)/norm  (ninv computed inline)
  {
    Job a = jz, b = jz;
    a.Alo = U2b; a.Ahi = U2b; a.Msplit = 4096; a.Bt = M2tb;
    a.bl = bl2; a.normsq = normsq2; a.bwdot = bwd2; a.bb = bb; a.which = 0;
    a.skey = s2key; a.N = 1024; a.K = 1152; a.nbx = 8;
    b.Alo = U1b; b.Ahi = U1b; b.Msplit = 16384; b.Bt = M1tb;
    b.bl = bl1; b.normsq = normsq1; b.bwdot = bwd1; b.bb = bb; b.which = 1;
    b.skey = s1key; b.N = 1024; b.K = 640; b.nbx = 8;
    k_gemm128<2><<<256 + 1024, 256, 0, stream>>>(a, b, 256);
  }

  // transfer + S1/S2 finalize (fused)
  k_tfold<<<7172, 256, 0, stream>>>(ref3, ref2, ref1, R3arg, s1key, s2key, out);
}